// Round 3
// baseline (1497.594 us; speedup 1.0000x reference)
//
#include <hip/hip_runtime.h>
#include <math.h>

#define NSAMP   661500
#define NFRAME  2584
#define NFTOT   20672

#define EN_OFF    82688
#define CEN_OFF   103360
#define TILT_OFF  124032
#define PITCH_OFF 144704
#define VOI_OFF   165376
#define RC_OFF    186048
#define XDS_OFF   806208

__device__ __forceinline__ float blockReduceSum(float v, float* s) {
  #pragma unroll
  for (int m = 1; m < 64; m <<= 1) v += __shfl_xor(v, m, 64);
  const int w = threadIdx.x >> 6;
  if ((threadIdx.x & 63) == 0) s[w] = v;
  __syncthreads();
  v = s[0] + s[1] + s[2] + s[3];
  __syncthreads();
  return v;
}

// Stockham radix-2 DIF, N=1024, forward (e^{-i}); verified by hand at N=4 and N=8.
__device__ __forceinline__ void fft1024(float2* X, float2* Y, const float2* tw, int tid) {
  int m = 1;
  #pragma unroll
  for (int s = 0; s < 10; ++s) {
    #pragma unroll
    for (int h = 0; h < 2; ++h) {
      const int t = tid + h * 256;
      const int k = t & (m - 1);
      const float2 c0 = X[t];
      const float2 c1 = X[t + 512];
      const float2 w  = tw[t - k];            // e^{+i th}; butterfly applies conj
      const float sx = c0.x + c1.x, sy = c0.y + c1.y;
      const float dx = c0.x - c1.x, dy = c0.y - c1.y;
      const float ox = dx * w.x + dy * w.y;
      const float oy = dy * w.x - dx * w.y;
      Y[2 * t - k]     = make_float2(sx, sy);
      Y[2 * t - k + m] = make_float2(ox, oy);
    }
    __syncthreads();
    float2* tmp = X; X = Y; Y = tmp;
    m <<= 1;
  }
}

// Double-precision Levinson matching the reference recurrence exactly.
template<int ORDER>
__device__ __forceinline__ void levinson_d(const double* r, double* a, float* gk) {
  double E = r[0];
  a[0] = 1.0;
  #pragma unroll
  for (int m = 1; m <= ORDER; ++m) {
    double acc = r[m];
    #pragma unroll
    for (int i = 1; i < m; ++i) acc += a[i] * r[m - i];
    const double kk = -acc / (E + 1e-9);
    #pragma unroll
    for (int i = 1; i <= (m - 1) / 2; ++i) {
      const double t1 = a[i], t2 = a[m - i];
      a[i]     = t1 + kk * t2;
      a[m - i] = t2 + kk * t1;
    }
    if ((m & 1) == 0) {
      const double t = a[m >> 1];
      a[m >> 1] = t + kk * t;
    }
    a[m] = kk;
    E *= (1.0 - kk * kk);
    if (gk) gk[m - 1] = (float)kk;
  }
}

__global__ void __launch_bounds__(256)
feat_main(const float* __restrict__ x, float* __restrict__ out,
          const int xds_pf, const int nccf_off) {
  __shared__ float2 A[1024];
  __shared__ float2 Bb[1024];
  __shared__ float2 tw[512];
  __shared__ float  Pw[513];
  __shared__ float  Pf[513];
  __shared__ float  sred[4];
  __shared__ int    sredi[4];

  const int tid = threadIdx.x;
  const int fg  = blockIdx.x;
  const int b   = fg / NFRAME;
  const int fr  = fg - b * NFRAME;
  const float* xb = x + (size_t)b * NSAMP;

  // twiddles: tw[t] = (cos, sin)(2*pi*t/1024)
  for (int t = tid; t < 512; t += 256) {
    const float th = (float)t * (6.2831853071795864769f / 1024.0f);
    float sn, cn;
    sincosf(th, &sn, &cn);
    tw[t] = make_float2(cn, sn);
  }

  // load frame + blackman window + energy
  float xfv[4], wv[4];
  float wsq = 0.0f, esum = 0.0f;
  #pragma unroll
  for (int q = 0; q < 4; ++q) {
    const int n = tid + q * 256;
    const float th = (float)n * (6.2831853071795864769f / 1023.0f);
    const float w = 0.42f - 0.5f * cosf(th) + 0.08f * cosf(2.0f * th);
    wv[q] = w;
    wsq += w * w;
    const int g = fr * 256 + n - 512;
    const float xv = (g >= 0 && g < NSAMP) ? xb[g] : 0.0f;
    xfv[q] = xv;
    esum += xv * xv;
  }
  const float invn = 1.0f / sqrtf(blockReduceSum(wsq, sred));
  const float en = blockReduceSum(esum, sred);
  if (tid == 0) out[EN_OFF + fg] = 10.0f * log10f(en + 1e-10f);
  #pragma unroll
  for (int q = 0; q < 4; ++q) {
    const int n = tid + q * 256;
    A[n] = make_float2(xfv[q] * wv[q] * invn, xfv[q]);  // z = xw + i*xf
  }
  __syncthreads();

  fft1024(A, Bb, tw, tid);  // packed spectra in A

  // unpack both spectra, power spectra, x_ds output, centroid sums
  float cs0 = 0.0f, cs1 = 0.0f;
  for (int k = tid; k < 513; k += 256) {
    const float2 Zk = A[k];
    const float2 Zn = A[(1024 - k) & 1023];
    const float xwr = 0.5f * (Zk.x + Zn.x);
    const float xwi = 0.5f * (Zk.y - Zn.y);
    const float xfr = 0.5f * (Zk.y + Zn.y);
    const float xfi = -0.5f * (Zk.x - Zn.x);
    const float pw = xwr * xwr + xwi * xwi;
    const float pf = xfr * xfr + xfi * xfi;
    Pw[k] = pw;
    Pf[k] = pf;
    const float mg = sqrtf(pf);
    cs0 += mg;
    cs1 += mg * ((float)k * (22050.0f / 1024.0f));
    if (k < 232) {
      if (xds_pf == 232) {
        out[XDS_OFF + (size_t)fg * 232 + k] = xwr;        // real part only
      } else {
        out[XDS_OFF + (size_t)fg * 464 + 2 * k]     = xwr;
        out[XDS_OFF + (size_t)fg * 464 + 2 * k + 1] = xwi;
      }
    }
  }
  const float csum0 = blockReduceSum(cs0, sred);
  const float csum1 = blockReduceSum(cs1, sred);
  if (tid == 0) out[CEN_OFF + fg] = csum1 / (csum0 + 1e-10f);

  // build packed extended power spectra (real-even): FFT = N * irfft
  #pragma unroll
  for (int q = 0; q < 4; ++q) {
    const int k = tid + q * 256;
    const int km = (k <= 512) ? k : (1024 - k);
    A[k] = make_float2(Pw[km] * 1024.0f, Pf[km]);
  }
  __syncthreads();

  fft1024(A, Bb, tw, tid);  // A[n].x = 2^20*ac_w[n], A[n].y = 1024*ac_f[n]

  // pitch: argmax over lags 44..441 (first-max tie-break)
  float pv = -3.0e38f;
  int   pl = 1 << 30;
  for (int l = 44 + tid; l <= 441; l += 256) {
    const float v = A[l].y;
    if (v > pv) { pv = v; pl = l; }
  }
  #pragma unroll
  for (int m = 1; m < 64; m <<= 1) {
    const float ov = __shfl_xor(pv, m, 64);
    const int   ol = __shfl_xor(pl, m, 64);
    if (ov > pv || (ov == pv && ol < pl)) { pv = ov; pl = ol; }
  }
  if ((tid & 63) == 0) { sred[tid >> 6] = pv; sredi[tid >> 6] = pl; }
  __syncthreads();
  if (tid == 0) {
    float bv = sred[0]; int bl = sredi[0];
    #pragma unroll
    for (int w = 1; w < 4; ++w)
      if (sred[w] > bv || (sred[w] == bv && sredi[w] < bl)) { bv = sred[w]; bl = sredi[w]; }
    const float ac0  = A[0].y * (1.0f / 1024.0f);
    const float peak = bv * (1.0f / 1024.0f);
    const float nccf = peak / (ac0 + 1e-9f);
    out[PITCH_OFF + fg] = logf(22050.0f / (float)bl);
    out[VOI_OFF + fg]   = (nccf > 0.3f) ? 1.0f : 0.0f;
    out[nccf_off + fg]  = nccf;
  }
  __syncthreads();  // protect sred reuse

  // ac_ds: 462-pt irfft of truncated power spectrum, lags 0..10
  float pwW = 0.0f;
  if (tid < 232) {
    const float wgt = (tid == 0 || tid == 231) ? 1.0f : 2.0f;
    pwW = Pw[tid] * wgt * (1.0f / 462.0f);
  }
  float acds[11];
  #pragma unroll
  for (int l = 0; l < 11; ++l) {
    const float term = pwW * cosf((float)(tid * l) * (6.2831853071795864769f / 462.0f));
    acds[l] = blockReduceSum(term, sred);
  }
  if (tid == 0) out[TILT_OFF + fg] = acds[1] / (acds[0] + 1e-10f);

  // ---- serial tail on wave 0, all in double (matches np-f64 reference) ----
  if (tid < 64) {
    double r30[31], a30[31];
    #pragma unroll
    for (int l = 0; l < 31; ++l) r30[l] = (double)A[l].x * (1.0 / 1048576.0);
    levinson_d<30>(r30, a30,
                   (tid == 0) ? (out + RC_OFF + (size_t)fg * 30) : (float*)nullptr);

    double rds[11], a10[11];
    #pragma unroll
    for (int l = 0; l < 11; ++l) rds[l] = (double)acds[l];
    levinson_d<10>(rds, a10, (float*)nullptr);

    // Durand-Kerner in f64: lane i owns root i (i<10), Jacobi update via shfl
    const int lane = tid;
    double zr = 0.4, zi = 0.9;
    for (int q = 0; q < lane; ++q) {
      const double nr = zr * 0.4 - zi * 0.9;
      zi = zr * 0.9 + zi * 0.4;
      zr = nr;
    }
    for (int it = 0; it < 60; ++it) {
      double pr = 1.0, pi = 0.0;            // Horner, c[0]=1
      #pragma unroll
      for (int q = 1; q <= 10; ++q) {
        const double nr = pr * zr - pi * zi + a10[q];
        pi = pr * zi + pi * zr;
        pr = nr;
      }
      double dr = 1.0, di = 0.0;
      #pragma unroll
      for (int j = 0; j < 10; ++j) {
        const double ozr = __shfl(zr, j, 64);
        const double ozi = __shfl(zi, j, 64);
        const double er = (j == lane) ? 1.0 : (zr - ozr);
        const double ei = (j == lane) ? 0.0 : (zi - ozi);
        const double nr = dr * er - di * ei;
        di = dr * ei + di * er;
        dr = nr;
      }
      dr += 1e-12;
      const double d2 = dr * dr + di * di;
      const double qr = (pr * dr + pi * di) / d2;
      const double qi = (pi * dr - pr * di) / d2;
      zr -= qr;
      zi -= qi;
    }
    const double ang = atan2(zi, zr);
    double freq = (ang > 0.0001) ? (ang / 6.283185307179586476925287 * 10000.0) : 5000.0;
    if (lane >= 10) freq = 1.0e300;
    double fsel[4];
    #pragma unroll
    for (int p = 0; p < 4; ++p) {
      double mn = freq;
      #pragma unroll
      for (int m = 1; m < 64; m <<= 1) mn = fmin(mn, __shfl_xor(mn, m, 64));
      fsel[p] = mn;
      const unsigned long long bal = __ballot(freq == mn);
      const int low = (int)__builtin_ctzll(bal);
      if (lane == low) freq = 1.0e300;
    }
    if (tid == 0) {
      out[fg * 4 + 0] = (float)fsel[0];
      out[fg * 4 + 1] = (float)fsel[1];
      out[fg * 4 + 2] = (float)fsel[2];
      out[fg * 4 + 3] = (float)fsel[3];
    }
  }
}

extern "C" void kernel_launch(void* const* d_in, const int* in_sizes, int n_in,
                              void* d_out, int out_size, void* d_ws, size_t ws_size,
                              hipStream_t stream) {
  (void)in_sizes; (void)n_in; (void)d_ws; (void)ws_size;
  const float* x = (const float*)d_in[0];
  float* out = (float*)d_out;
  // x_ds region layout derived from total out_size (real-only=232 or interleaved=464)
  int xds_pf = 232;
  if (out_size >= XDS_OFF + NFTOT * 464 + NFTOT) xds_pf = 464;
  const int nccf_off = XDS_OFF + NFTOT * xds_pf;
  feat_main<<<dim3(NFTOT), dim3(256), 0, stream>>>(x, out, xds_pf, nccf_off);
}

// Round 7
// 1049.652 us; speedup vs baseline: 1.4268x; 1.4268x over previous
//
#include <hip/hip_runtime.h>
#include <math.h>

#define NSAMP   661500
#define NFRAME  2584
#define NFTOT   20672

#define EN_OFF    82688
#define CEN_OFF   103360
#define TILT_OFF  124032
#define PITCH_OFF 144704
#define VOI_OFF   165376
#define RC_OFF    186048
#define XDS_OFF   806208

__device__ __forceinline__ float blockReduceSum(float v, float* s) {
  #pragma unroll
  for (int m = 1; m < 64; m <<= 1) v += __shfl_xor(v, m, 64);
  const int w = threadIdx.x >> 6;
  if ((threadIdx.x & 63) == 0) s[w] = v;
  __syncthreads();
  v = s[0] + s[1] + s[2] + s[3];
  __syncthreads();
  return v;
}

// Stockham radix-2 DIF, N=1024, forward (e^{-i}).
__device__ __forceinline__ void fft1024(float2* X, float2* Y, const float2* tw, int tid) {
  int m = 1;
  #pragma unroll
  for (int s = 0; s < 10; ++s) {
    #pragma unroll
    for (int h = 0; h < 2; ++h) {
      const int t = tid + h * 256;
      const int k = t & (m - 1);
      const float2 c0 = X[t];
      const float2 c1 = X[t + 512];
      const float2 w  = tw[t - k];            // e^{+i th}; butterfly applies conj
      const float sx = c0.x + c1.x, sy = c0.y + c1.y;
      const float dx = c0.x - c1.x, dy = c0.y - c1.y;
      const float ox = dx * w.x + dy * w.y;
      const float oy = dy * w.x - dx * w.y;
      Y[2 * t - k]     = make_float2(sx, sy);
      Y[2 * t - k + m] = make_float2(ox, oy);
    }
    __syncthreads();
    float2* tmp = X; X = Y; Y = tmp;
    m <<= 1;
  }
}

// f64 Levinson matching the reference recurrence (used for order 10 -> DK).
template<int ORDER>
__device__ __forceinline__ void levinson_d(const double* r, double* a, float* gk) {
  double E = r[0];
  a[0] = 1.0;
  #pragma unroll
  for (int m = 1; m <= ORDER; ++m) {
    double acc = r[m];
    #pragma unroll
    for (int i = 1; i < m; ++i) acc += a[i] * r[m - i];
    const double kk = -acc / (E + 1e-9);
    #pragma unroll
    for (int i = 1; i <= (m - 1) / 2; ++i) {
      const double t1 = a[i], t2 = a[m - i];
      a[i]     = t1 + kk * t2;
      a[m - i] = t2 + kk * t1;
    }
    if ((m & 1) == 0) {
      const double t = a[m >> 1];
      a[m >> 1] = t + kk * t;
    }
    a[m] = kk;
    E *= (1.0 - kk * kk);
    if (gk) gk[m - 1] = (float)kk;
  }
}

// f32 Levinson (order 30, rc output only; |k|<=1, threshold ~0.03 >> f32 err)
template<int ORDER>
__device__ __forceinline__ void levinson_f(const float* r, float* a, float* gk) {
  float E = r[0];
  a[0] = 1.0f;
  #pragma unroll
  for (int m = 1; m <= ORDER; ++m) {
    float acc = r[m];
    #pragma unroll
    for (int i = 1; i < m; ++i) acc += a[i] * r[m - i];
    const float kk = -acc / (E + 1e-9f);
    #pragma unroll
    for (int i = 1; i <= (m - 1) / 2; ++i) {
      const float t1 = a[i], t2 = a[m - i];
      a[i]     = t1 + kk * t2;
      a[m - i] = t2 + kk * t1;
    }
    if ((m & 1) == 0) {
      const float t = a[m >> 1];
      a[m >> 1] = t + kk * t;
    }
    a[m] = kk;
    E *= (1.0f - kk * kk);
    if (gk) gk[m - 1] = kk;
  }
}

__global__ void __launch_bounds__(256)
feat_main(const float* __restrict__ x, float* __restrict__ out,
          const int xds_pf, const int nccf_off) {
  __shared__ float2 A[1024];
  __shared__ float2 Bb[1024];
  __shared__ float2 tw[512];
  __shared__ float  Pw[513];
  __shared__ float  Pf[513];
  __shared__ float  sred[4];
  __shared__ int    sredi[4];

  const int tid = threadIdx.x;
  const int fg  = blockIdx.x;
  const int b   = fg / NFRAME;
  const int fr  = fg - b * NFRAME;
  const float* xb = x + (size_t)b * NSAMP;

  // twiddles: tw[t] = (cos, sin)(2*pi*t/1024)
  for (int t = tid; t < 512; t += 256) {
    const float th = (float)t * (6.2831853071795864769f / 1024.0f);
    float sn, cn;
    sincosf(th, &sn, &cn);
    tw[t] = make_float2(cn, sn);
  }

  // load frame + blackman window + energy
  float xfv[4], wv[4];
  float wsq = 0.0f, esum = 0.0f;
  #pragma unroll
  for (int q = 0; q < 4; ++q) {
    const int n = tid + q * 256;
    const float th = (float)n * (6.2831853071795864769f / 1023.0f);
    const float w = 0.42f - 0.5f * cosf(th) + 0.08f * cosf(2.0f * th);
    wv[q] = w;
    wsq += w * w;
    const int g = fr * 256 + n - 512;
    const float xv = (g >= 0 && g < NSAMP) ? xb[g] : 0.0f;
    xfv[q] = xv;
    esum += xv * xv;
  }
  const float invn = 1.0f / sqrtf(blockReduceSum(wsq, sred));
  const float en = blockReduceSum(esum, sred);
  if (tid == 0) out[EN_OFF + fg] = 10.0f * log10f(en + 1e-10f);
  #pragma unroll
  for (int q = 0; q < 4; ++q) {
    const int n = tid + q * 256;
    A[n] = make_float2(xfv[q] * wv[q] * invn, xfv[q]);  // z = xw + i*xf
  }
  __syncthreads();

  fft1024(A, Bb, tw, tid);  // packed spectra in A

  // unpack both spectra, power spectra, x_ds output, centroid sums
  float cs0 = 0.0f, cs1 = 0.0f;
  for (int k = tid; k < 513; k += 256) {
    const float2 Zk = A[k];
    const float2 Zn = A[(1024 - k) & 1023];
    const float xwr = 0.5f * (Zk.x + Zn.x);
    const float xwi = 0.5f * (Zk.y - Zn.y);
    const float xfr = 0.5f * (Zk.y + Zn.y);
    const float xfi = -0.5f * (Zk.x - Zn.x);
    const float pw = xwr * xwr + xwi * xwi;
    const float pf = xfr * xfr + xfi * xfi;
    Pw[k] = pw;
    Pf[k] = pf;
    const float mg = sqrtf(pf);
    cs0 += mg;
    cs1 += mg * ((float)k * (22050.0f / 1024.0f));
    if (k < 232) {
      if (xds_pf == 232) {
        out[XDS_OFF + (size_t)fg * 232 + k] = xwr;        // real part only
      } else {
        out[XDS_OFF + (size_t)fg * 464 + 2 * k]     = xwr;
        out[XDS_OFF + (size_t)fg * 464 + 2 * k + 1] = xwi;
      }
    }
  }
  const float csum0 = blockReduceSum(cs0, sred);
  const float csum1 = blockReduceSum(cs1, sred);
  if (tid == 0) out[CEN_OFF + fg] = csum1 / (csum0 + 1e-10f);

  // build packed extended power spectra (real-even): FFT = N * irfft
  #pragma unroll
  for (int q = 0; q < 4; ++q) {
    const int k = tid + q * 256;
    const int km = (k <= 512) ? k : (1024 - k);
    A[k] = make_float2(Pw[km] * 1024.0f, Pf[km]);
  }
  __syncthreads();

  fft1024(A, Bb, tw, tid);  // A[n].x = 2^20*ac_w[n], A[n].y = 1024*ac_f[n]

  // pitch: argmax over lags 44..441 (first-max tie-break)
  float pv = -3.0e38f;
  int   pl = 1 << 30;
  for (int l = 44 + tid; l <= 441; l += 256) {
    const float v = A[l].y;
    if (v > pv) { pv = v; pl = l; }
  }
  #pragma unroll
  for (int m = 1; m < 64; m <<= 1) {
    const float ov = __shfl_xor(pv, m, 64);
    const int   ol = __shfl_xor(pl, m, 64);
    if (ov > pv || (ov == pv && ol < pl)) { pv = ov; pl = ol; }
  }
  if ((tid & 63) == 0) { sred[tid >> 6] = pv; sredi[tid >> 6] = pl; }
  __syncthreads();
  if (tid == 0) {
    float bv = sred[0]; int bl = sredi[0];
    #pragma unroll
    for (int w = 1; w < 4; ++w)
      if (sred[w] > bv || (sred[w] == bv && sredi[w] < bl)) { bv = sred[w]; bl = sredi[w]; }
    const float ac0  = A[0].y * (1.0f / 1024.0f);
    const float peak = bv * (1.0f / 1024.0f);
    const float nccf = peak / (ac0 + 1e-9f);
    out[PITCH_OFF + fg] = logf(22050.0f / (float)bl);
    out[VOI_OFF + fg]   = (nccf > 0.3f) ? 1.0f : 0.0f;
    out[nccf_off + fg]  = nccf;
  }
  __syncthreads();  // protect sred reuse

  // ac_ds: 462-pt irfft of truncated power spectrum, lags 0..10
  float pwW = 0.0f;
  if (tid < 232) {
    const float wgt = (tid == 0 || tid == 231) ? 1.0f : 2.0f;
    pwW = Pw[tid] * wgt * (1.0f / 462.0f);
  }
  float acds[11];
  #pragma unroll
  for (int l = 0; l < 11; ++l) {
    const float term = pwW * cosf((float)(tid * l) * (6.2831853071795864769f / 462.0f));
    acds[l] = blockReduceSum(term, sred);
  }
  if (tid == 0) out[TILT_OFF + fg] = acds[1] / (acds[0] + 1e-10f);

  // ---- serial tail on wave 0 (L30 f32; L10 + DK f64 for the angle cliff) ----
  if (tid < 64) {
    float r30[31], a30[31];
    #pragma unroll
    for (int l = 0; l < 31; ++l) r30[l] = A[l].x * (1.0f / 1048576.0f);
    levinson_f<30>(r30, a30,
                   (tid == 0) ? (out + RC_OFF + (size_t)fg * 30) : (float*)nullptr);

    double rds[11], a10[11];
    #pragma unroll
    for (int l = 0; l < 11; ++l) rds[l] = (double)acds[l];
    levinson_d<10>(rds, a10, (float*)nullptr);

    // Durand-Kerner in f64: lane i owns root i (i<10), Jacobi update via shfl
    const int lane = tid;
    double zr = 0.4, zi = 0.9;
    for (int q = 0; q < lane; ++q) {
      const double nr = zr * 0.4 - zi * 0.9;
      zi = zr * 0.9 + zi * 0.4;
      zr = nr;
    }
    for (int it = 0; it < 60; ++it) {
      double pr = 1.0, pi = 0.0;            // Horner, c[0]=1
      #pragma unroll
      for (int q = 1; q <= 10; ++q) {
        const double nr = pr * zr - pi * zi + a10[q];
        pi = pr * zi + pi * zr;
        pr = nr;
      }
      double dr = 1.0, di = 0.0;
      #pragma unroll
      for (int j = 0; j < 10; ++j) {
        const double ozr = __shfl(zr, j, 64);
        const double ozi = __shfl(zi, j, 64);
        const double er = (j == lane) ? 1.0 : (zr - ozr);
        const double ei = (j == lane) ? 0.0 : (zi - ozi);
        const double nr = dr * er - di * ei;
        di = dr * ei + di * er;
        dr = nr;
      }
      dr += 1e-12;
      const double d2 = dr * dr + di * di;
      const double qr = (pr * dr + pi * di) / d2;
      const double qi = (pi * dr - pr * di) / d2;
      zr -= qr;
      zi -= qi;
    }
    const double ang = atan2(zi, zr);
    double freq = (ang > 0.0001) ? (ang / 6.283185307179586476925287 * 10000.0) : 5000.0;
    if (lane >= 10) freq = 1.0e300;
    double fsel[4];
    #pragma unroll
    for (int p = 0; p < 4; ++p) {
      double mn = freq;
      #pragma unroll
      for (int m = 1; m < 64; m <<= 1) mn = fmin(mn, __shfl_xor(mn, m, 64));
      fsel[p] = mn;
      const unsigned long long bal = __ballot(freq == mn);
      const int low = (int)__builtin_ctzll(bal);
      if (lane == low) freq = 1.0e300;
    }
    if (tid == 0) {
      out[fg * 4 + 0] = (float)fsel[0];
      out[fg * 4 + 1] = (float)fsel[1];
      out[fg * 4 + 2] = (float)fsel[2];
      out[fg * 4 + 3] = (float)fsel[3];
    }
  }
}

extern "C" void kernel_launch(void* const* d_in, const int* in_sizes, int n_in,
                              void* d_out, int out_size, void* d_ws, size_t ws_size,
                              hipStream_t stream) {
  (void)in_sizes; (void)n_in; (void)d_ws; (void)ws_size;
  const float* x = (const float*)d_in[0];
  float* out = (float*)d_out;
  // x_ds region layout derived from total out_size (real-only=232 or interleaved=464)
  int xds_pf = 232;
  if (out_size >= XDS_OFF + NFTOT * 464 + NFTOT) xds_pf = 464;
  const int nccf_off = XDS_OFF + NFTOT * xds_pf;
  feat_main<<<dim3(NFTOT), dim3(256), 0, stream>>>(x, out, xds_pf, nccf_off);
}

// Round 8
// 880.875 us; speedup vs baseline: 1.7001x; 1.1916x over previous
//
#include <hip/hip_runtime.h>
#include <math.h>

#define NSAMP   661500
#define NFRAME  2584
#define NFTOT   20672

#define EN_OFF    82688
#define CEN_OFF   103360
#define TILT_OFF  124032
#define PITCH_OFF 144704
#define VOI_OFF   165376
#define RC_OFF    186048
#define XDS_OFF   806208

__device__ __forceinline__ float blockReduceSum(float v, float* s) {
  #pragma unroll
  for (int m = 1; m < 64; m <<= 1) v += __shfl_xor(v, m, 64);
  const int w = threadIdx.x >> 6;
  if ((threadIdx.x & 63) == 0) s[w] = v;
  __syncthreads();
  v = s[0] + s[1] + s[2] + s[3];
  __syncthreads();
  return v;
}

// Stockham radix-2 DIF, N=1024, forward (e^{-i}).
__device__ __forceinline__ void fft1024(float2* X, float2* Y, const float2* tw, int tid) {
  int m = 1;
  #pragma unroll
  for (int s = 0; s < 10; ++s) {
    #pragma unroll
    for (int h = 0; h < 2; ++h) {
      const int t = tid + h * 256;
      const int k = t & (m - 1);
      const float2 c0 = X[t];
      const float2 c1 = X[t + 512];
      const float2 w  = tw[t - k];            // e^{+i th}; butterfly applies conj
      const float sx = c0.x + c1.x, sy = c0.y + c1.y;
      const float dx = c0.x - c1.x, dy = c0.y - c1.y;
      const float ox = dx * w.x + dy * w.y;
      const float oy = dy * w.x - dx * w.y;
      Y[2 * t - k]     = make_float2(sx, sy);
      Y[2 * t - k + m] = make_float2(ox, oy);
    }
    __syncthreads();
    float2* tmp = X; X = Y; Y = tmp;
    m <<= 1;
  }
}

// f64 Levinson matching the reference recurrence (order 10 -> DK).
template<int ORDER>
__device__ __forceinline__ void levinson_d(const double* r, double* a, float* gk) {
  double E = r[0];
  a[0] = 1.0;
  #pragma unroll
  for (int m = 1; m <= ORDER; ++m) {
    double acc = r[m];
    #pragma unroll
    for (int i = 1; i < m; ++i) acc += a[i] * r[m - i];
    const double kk = -acc / (E + 1e-9);
    #pragma unroll
    for (int i = 1; i <= (m - 1) / 2; ++i) {
      const double t1 = a[i], t2 = a[m - i];
      a[i]     = t1 + kk * t2;
      a[m - i] = t2 + kk * t1;
    }
    if ((m & 1) == 0) {
      const double t = a[m >> 1];
      a[m >> 1] = t + kk * t;
    }
    a[m] = kk;
    E *= (1.0 - kk * kk);
    if (gk) gk[m - 1] = (float)kk;
  }
}

// f32 Levinson (order 30, rc output only; |k|<=1, threshold ~0.03 >> f32 err)
template<int ORDER>
__device__ __forceinline__ void levinson_f(const float* r, float* a, float* gk) {
  float E = r[0];
  a[0] = 1.0f;
  #pragma unroll
  for (int m = 1; m <= ORDER; ++m) {
    float acc = r[m];
    #pragma unroll
    for (int i = 1; i < m; ++i) acc += a[i] * r[m - i];
    const float kk = -acc / (E + 1e-9f);
    #pragma unroll
    for (int i = 1; i <= (m - 1) / 2; ++i) {
      const float t1 = a[i], t2 = a[m - i];
      a[i]     = t1 + kk * t2;
      a[m - i] = t2 + kk * t1;
    }
    if ((m & 1) == 0) {
      const float t = a[m >> 1];
      a[m >> 1] = t + kk * t;
    }
    a[m] = kk;
    E *= (1.0f - kk * kk);
    if (gk) gk[m - 1] = kk;
  }
}

// One block = 4 consecutive frames; per-frame math bit-identical to the
// passing round-7 kernel; f64 tails deferred so all 4 waves run concurrently.
__global__ void __launch_bounds__(256)
feat_mono4(const float* __restrict__ x, float* __restrict__ out,
           const int xds_pf, const int nccf_off) {
  __shared__ float2 A[1024];
  __shared__ float2 Bb[1024];
  __shared__ float2 tw[512];
  __shared__ float  Pw[513];
  __shared__ float  Pf[513];
  __shared__ float  sred[4];
  __shared__ int    sredi[4];
  __shared__ float  stash[4][42];   // [phase][0..30]=2^20*ac_w, [31..41]=acds

  const int tid   = threadIdx.x;
  const int w     = tid >> 6;
  const int lane  = tid & 63;
  const int fbase = blockIdx.x * 4;

  // twiddles once per block
  for (int t = tid; t < 512; t += 256) {
    const float th = (float)t * (6.2831853071795864769f / 1024.0f);
    float sn, cn;
    sincosf(th, &sn, &cn);
    tw[t] = make_float2(cn, sn);
  }

  // blackman window + invn once (frame-independent)
  float wv[4];
  float wsq = 0.0f;
  #pragma unroll
  for (int q = 0; q < 4; ++q) {
    const int n = tid + q * 256;
    const float th = (float)n * (6.2831853071795864769f / 1023.0f);
    const float wn = 0.42f - 0.5f * cosf(th) + 0.08f * cosf(2.0f * th);
    wv[q] = wn;
    wsq += wn * wn;
  }
  __syncthreads();   // tw ready
  const float invn = 1.0f / sqrtf(blockReduceSum(wsq, sred));

  #pragma unroll 1
  for (int p = 0; p < 4; ++p) {
    const int fg = fbase + p;
    const int bb = fg / NFRAME;
    const int fr = fg - bb * NFRAME;
    const float* xb = x + (size_t)bb * NSAMP;

    // load frame + energy
    float xfv[4];
    float esum = 0.0f;
    #pragma unroll
    for (int q = 0; q < 4; ++q) {
      const int n = tid + q * 256;
      const int g = fr * 256 + n - 512;
      const float xv = (g >= 0 && g < NSAMP) ? xb[g] : 0.0f;
      xfv[q] = xv;
      esum += xv * xv;
    }
    const float en = blockReduceSum(esum, sred);
    if (tid == 0) out[EN_OFF + fg] = 10.0f * log10f(en + 1e-10f);
    #pragma unroll
    for (int q = 0; q < 4; ++q) {
      const int n = tid + q * 256;
      A[n] = make_float2(xfv[q] * wv[q] * invn, xfv[q]);  // z = xw + i*xf
    }
    __syncthreads();

    fft1024(A, Bb, tw, tid);  // packed spectra in A

    // unpack spectra, power spectra, x_ds output, centroid sums
    float cs0 = 0.0f, cs1 = 0.0f;
    for (int k = tid; k < 513; k += 256) {
      const float2 Zk = A[k];
      const float2 Zn = A[(1024 - k) & 1023];
      const float xwr = 0.5f * (Zk.x + Zn.x);
      const float xwi = 0.5f * (Zk.y - Zn.y);
      const float xfr = 0.5f * (Zk.y + Zn.y);
      const float xfi = -0.5f * (Zk.x - Zn.x);
      const float pw = xwr * xwr + xwi * xwi;
      const float pf = xfr * xfr + xfi * xfi;
      Pw[k] = pw;
      Pf[k] = pf;
      const float mg = sqrtf(pf);
      cs0 += mg;
      cs1 += mg * ((float)k * (22050.0f / 1024.0f));
      if (k < 232) {
        if (xds_pf == 232) {
          out[XDS_OFF + (size_t)fg * 232 + k] = xwr;
        } else {
          out[XDS_OFF + (size_t)fg * 464 + 2 * k]     = xwr;
          out[XDS_OFF + (size_t)fg * 464 + 2 * k + 1] = xwi;
        }
      }
    }
    const float csum0 = blockReduceSum(cs0, sred);
    const float csum1 = blockReduceSum(cs1, sred);
    if (tid == 0) out[CEN_OFF + fg] = csum1 / (csum0 + 1e-10f);
    // (reduce barriers make Pw/Pf visible and A fully consumed)

    // packed extended power spectra (real-even): FFT = N * irfft
    #pragma unroll
    for (int q = 0; q < 4; ++q) {
      const int k = tid + q * 256;
      const int km = (k <= 512) ? k : (1024 - k);
      A[k] = make_float2(Pw[km] * 1024.0f, Pf[km]);
    }
    __syncthreads();

    fft1024(A, Bb, tw, tid);  // A[n].x = 2^20*ac_w[n], A[n].y = 1024*ac_f[n]

    // pitch: argmax lags 44..441 (first-max tie-break)
    float pv = -3.0e38f;
    int   pl = 1 << 30;
    for (int l = 44 + tid; l <= 441; l += 256) {
      const float v = A[l].y;
      if (v > pv) { pv = v; pl = l; }
    }
    #pragma unroll
    for (int m = 1; m < 64; m <<= 1) {
      const float ov = __shfl_xor(pv, m, 64);
      const int   ol = __shfl_xor(pl, m, 64);
      if (ov > pv || (ov == pv && ol < pl)) { pv = ov; pl = ol; }
    }
    if (lane == 0) { sred[w] = pv; sredi[w] = pl; }
    __syncthreads();
    if (tid == 0) {
      float bv = sred[0]; int bl = sredi[0];
      #pragma unroll
      for (int q = 1; q < 4; ++q)
        if (sred[q] > bv || (sred[q] == bv && sredi[q] < bl)) { bv = sred[q]; bl = sredi[q]; }
      const float ac0  = A[0].y * (1.0f / 1024.0f);
      const float peak = bv * (1.0f / 1024.0f);
      const float nccf = peak / (ac0 + 1e-9f);
      out[PITCH_OFF + fg] = logf(22050.0f / (float)bl);
      out[VOI_OFF + fg]   = (nccf > 0.3f) ? 1.0f : 0.0f;
      out[nccf_off + fg]  = nccf;
    }
    __syncthreads();  // protect sred reuse

    // ac_ds lags 0..10 — SAME 256-thread reduce grouping as round 7 (bit-identical)
    float pwW = 0.0f;
    if (tid < 232) {
      const float wgt = (tid == 0 || tid == 231) ? 1.0f : 2.0f;
      pwW = Pw[tid] * wgt * (1.0f / 462.0f);
    }
    #pragma unroll
    for (int l = 0; l < 11; ++l) {
      const float term = pwW * cosf((float)(tid * l) * (6.2831853071795864769f / 462.0f));
      const float t = blockReduceSum(term, sred);
      if (tid == 0) stash[p][31 + l] = t;
    }
    if (tid == 0) out[TILT_OFF + fg] = stash[p][32] / (stash[p][31] + 1e-10f);
    if (tid < 31) stash[p][tid] = A[tid].x;   // 2^20 * ac_w (A intact since 2nd fft)
    __syncthreads();   // phase end: stash visible, A/Pw free for next phase
  }

  // ---- deferred tails: all 4 waves concurrently, no barriers below ----
  {
    const int fg = fbase + w;

    float r30[31], a30[31];
    #pragma unroll
    for (int l = 0; l < 31; ++l) r30[l] = stash[w][l] * (1.0f / 1048576.0f);
    levinson_f<30>(r30, a30,
                   (lane == 0) ? (out + RC_OFF + (size_t)fg * 30) : (float*)nullptr);

    double rds[11], a10[11];
    #pragma unroll
    for (int l = 0; l < 11; ++l) rds[l] = (double)stash[w][31 + l];
    levinson_d<10>(rds, a10, (float*)nullptr);

    // Durand-Kerner in f64: lane i owns root i (i<10), Jacobi update via shfl
    double zr = 0.4, zi = 0.9;
    for (int q = 0; q < lane; ++q) {
      const double nr = zr * 0.4 - zi * 0.9;
      zi = zr * 0.9 + zi * 0.4;
      zr = nr;
    }
    for (int it = 0; it < 60; ++it) {
      double pr = 1.0, pi = 0.0;            // Horner, c[0]=1
      #pragma unroll
      for (int q = 1; q <= 10; ++q) {
        const double nr = pr * zr - pi * zi + a10[q];
        pi = pr * zi + pi * zr;
        pr = nr;
      }
      double dr = 1.0, di = 0.0;
      #pragma unroll
      for (int j = 0; j < 10; ++j) {
        const double ozr = __shfl(zr, j, 64);
        const double ozi = __shfl(zi, j, 64);
        const double er = (j == lane) ? 1.0 : (zr - ozr);
        const double ei = (j == lane) ? 0.0 : (zi - ozi);
        const double nr = dr * er - di * ei;
        di = dr * ei + di * er;
        dr = nr;
      }
      dr += 1e-12;
      const double d2 = dr * dr + di * di;
      const double qr = (pr * dr + pi * di) / d2;
      const double qi = (pi * dr - pr * di) / d2;
      zr -= qr;
      zi -= qi;
    }
    const double ang = atan2(zi, zr);
    double freq = (ang > 0.0001) ? (ang / 6.283185307179586476925287 * 10000.0) : 5000.0;
    if (lane >= 10) freq = 1.0e300;
    double fsel[4];
    #pragma unroll
    for (int p2 = 0; p2 < 4; ++p2) {
      double mn = freq;
      #pragma unroll
      for (int m = 1; m < 64; m <<= 1) mn = fmin(mn, __shfl_xor(mn, m, 64));
      fsel[p2] = mn;
      const unsigned long long bal = __ballot(freq == mn);
      const int low = (int)__builtin_ctzll(bal);
      if (lane == low) freq = 1.0e300;
    }
    if (lane == 0) {
      out[(size_t)fg * 4 + 0] = (float)fsel[0];
      out[(size_t)fg * 4 + 1] = (float)fsel[1];
      out[(size_t)fg * 4 + 2] = (float)fsel[2];
      out[(size_t)fg * 4 + 3] = (float)fsel[3];
    }
  }
}

extern "C" void kernel_launch(void* const* d_in, const int* in_sizes, int n_in,
                              void* d_out, int out_size, void* d_ws, size_t ws_size,
                              hipStream_t stream) {
  (void)in_sizes; (void)n_in; (void)d_ws; (void)ws_size;
  const float* x = (const float*)d_in[0];
  float* out = (float*)d_out;
  int xds_pf = 232;
  if (out_size >= XDS_OFF + NFTOT * 464 + NFTOT) xds_pf = 464;
  const int nccf_off = XDS_OFF + NFTOT * xds_pf;
  feat_mono4<<<dim3(NFTOT / 4), dim3(256), 0, stream>>>(x, out, xds_pf, nccf_off);
}

// Round 9
// 755.031 us; speedup vs baseline: 1.9835x; 1.1667x over previous
//
#include <hip/hip_runtime.h>
#include <math.h>

#define NSAMP   661500
#define NFRAME  2584
#define NFTOT   20672

#define EN_OFF    82688
#define CEN_OFF   103360
#define TILT_OFF  124032
#define PITCH_OFF 144704
#define VOI_OFF   165376
#define RC_OFF    186048
#define XDS_OFF   806208

__device__ __forceinline__ float waveReduceSum(float v) {
  #pragma unroll
  for (int m = 1; m < 64; m <<= 1) v += __shfl_xor(v, m, 64);
  return v;
}

__device__ __forceinline__ float blockReduceSum(float v, float* s) {
  v = waveReduceSum(v);
  const int w = threadIdx.x >> 6;
  if ((threadIdx.x & 63) == 0) s[w] = v;
  __syncthreads();
  v = s[0] + s[1] + s[2] + s[3];
  __syncthreads();
  return v;
}

// two reductions sharing one barrier pair; same per-value add order as blockReduceSum
__device__ __forceinline__ void blockReduceSum2(float& v0, float& v1, float* s) {
  v0 = waveReduceSum(v0);
  v1 = waveReduceSum(v1);
  const int w = threadIdx.x >> 6;
  if ((threadIdx.x & 63) == 0) { s[w] = v0; s[4 + w] = v1; }
  __syncthreads();
  v0 = s[0] + s[1] + s[2] + s[3];
  v1 = s[4] + s[5] + s[6] + s[7];
  __syncthreads();
}

// Stockham radix-2 DIF, N=1024, forward (e^{-i}), TWO stages fused per barrier.
// 5 barriers; result ends in Y (the second buffer passed by the caller).
// Derivation: stage pair with m in {1,4,16,64,256}; t=tid, k=t&(m-1), jm=t-k;
// stage-1 butterflies (t, t+512) and (t+256, t+768) with twiddles tw[jm], i*tw[jm];
// stage-2 both butterflies use tw[2jm] = tw[jm]^2; outputs at B+{0,m,2m,3m}, B=4t-3k.
__device__ __forceinline__ void fft1024p(float2* X, float2* Y, const float2* tw, int tid) {
  int m = 1;
  #pragma unroll
  for (int s = 0; s < 5; ++s) {
    const int k  = tid & (m - 1);
    const int jm = tid - k;
    const float2 a0 = X[tid];
    const float2 a1 = X[tid + 256];
    const float2 a2 = X[tid + 512];
    const float2 a3 = X[tid + 768];
    const float2 w1 = tw[jm];
    float2 sA, dA, sB, dB;
    sA.x = a0.x + a2.x; sA.y = a0.y + a2.y;
    { const float dx = a0.x - a2.x, dy = a0.y - a2.y;
      dA.x = dx * w1.x + dy * w1.y;            // d * conj(w1)
      dA.y = dy * w1.x - dx * w1.y; }
    sB.x = a1.x + a3.x; sB.y = a1.y + a3.y;
    { const float dx = a1.x - a3.x, dy = a1.y - a3.y;
      const float wx = -w1.y, wy = w1.x;       // i * w1
      dB.x = dx * wx + dy * wy;
      dB.y = dy * wx - dx * wy; }
    const float w2x = w1.x * w1.x - w1.y * w1.y;   // w1^2
    const float w2y = 2.0f * w1.x * w1.y;
    const int B = 4 * tid - 3 * k;
    { float2 o;
      o.x = sA.x + sB.x; o.y = sA.y + sB.y;
      Y[B] = o;
      const float dx = sA.x - sB.x, dy = sA.y - sB.y;
      o.x = dx * w2x + dy * w2y;
      o.y = dy * w2x - dx * w2y;
      Y[B + 2 * m] = o; }
    { float2 o;
      o.x = dA.x + dB.x; o.y = dA.y + dB.y;
      Y[B + m] = o;
      const float dx = dA.x - dB.x, dy = dA.y - dB.y;
      o.x = dx * w2x + dy * w2y;
      o.y = dy * w2x - dx * w2y;
      Y[B + 3 * m] = o; }
    __syncthreads();
    float2* tmp = X; X = Y; Y = tmp;
    m <<= 2;
  }
}

// f64 Levinson matching the reference recurrence (order 10 -> DK).
template<int ORDER>
__device__ __forceinline__ void levinson_d(const double* r, double* a) {
  double E = r[0];
  a[0] = 1.0;
  #pragma unroll
  for (int m = 1; m <= ORDER; ++m) {
    double acc = r[m];
    #pragma unroll
    for (int i = 1; i < m; ++i) acc += a[i] * r[m - i];
    const double kk = -acc / (E + 1e-9);
    #pragma unroll
    for (int i = 1; i <= (m - 1) / 2; ++i) {
      const double t1 = a[i], t2 = a[m - i];
      a[i]     = t1 + kk * t2;
      a[m - i] = t2 + kk * t1;
    }
    if ((m & 1) == 0) { const double t = a[m >> 1]; a[m >> 1] = t + kk * t; }
    a[m] = kk;
    E *= (1.0 - kk * kk);
  }
}

// f32 Levinson, order 30, rc out; r read from LDS (saves 31 VGPRs).
__device__ __forceinline__ void levinson_f30(const float* r, float* gk) {
  float a[31];
  float E = r[0];
  a[0] = 1.0f;
  #pragma unroll
  for (int m = 1; m <= 30; ++m) {
    float acc = r[m];
    #pragma unroll
    for (int i = 1; i < m; ++i) acc += a[i] * r[m - i];
    const float kk = -acc / (E + 1e-9f);
    #pragma unroll
    for (int i = 1; i <= (m - 1) / 2; ++i) {
      const float t1 = a[i], t2 = a[m - i];
      a[i]     = t1 + kk * t2;
      a[m - i] = t2 + kk * t1;
    }
    if ((m & 1) == 0) { const float t = a[m >> 1]; a[m >> 1] = t + kk * t; }
    a[m] = kk;
    E *= (1.0f - kk * kk);
    if (gk) gk[m - 1] = kk;
  }
}

__global__ void __launch_bounds__(256, 6)
feat_mono4(const float* __restrict__ x, float* __restrict__ out,
           const int xds_pf, const int nccf_off) {
  __shared__ float2 A[1024];
  __shared__ float2 Bb[1024];
  __shared__ float2 tw[256];
  __shared__ float  Pw[232];
  __shared__ float  sred[8];
  __shared__ int    sredi[4];
  __shared__ float  stash[4][42];   // [phase][0..30]=r30 (normalized), [31..41]=acds
  __shared__ float  aprt[4][11];

  const int tid   = threadIdx.x;
  const int w     = tid >> 6;
  const int lane  = tid & 63;
  const int fbase = blockIdx.x * 4;

  // ---- per-block prologue (amortized over 4 frames) ----
  {
    const float th = (float)tid * (6.2831853071795864769f / 1024.0f);
    float sn, cn;
    sincosf(th, &sn, &cn);
    tw[tid] = make_float2(cn, sn);
  }
  float wv[4];
  float wsq = 0.0f;
  #pragma unroll
  for (int q = 0; q < 4; ++q) {
    const int n = tid + q * 256;
    const float th = (float)n * (6.2831853071795864769f / 1023.0f);
    const float wn = 0.42f - 0.5f * cosf(th) + 0.08f * cosf(2.0f * th);
    wv[q] = wn;
    wsq += wn * wn;
  }
  float ctab[11];
  #pragma unroll
  for (int l = 0; l < 11; ++l)
    ctab[l] = cosf((float)(tid * l) * (6.2831853071795864769f / 462.0f));
  const float wgt462 = ((tid == 0 || tid == 231) ? 1.0f : 2.0f) * (1.0f / 462.0f);
  __syncthreads();   // tw visible
  const float invn = 1.0f / sqrtf(blockReduceSum(wsq, sred));

  #pragma unroll 1
  for (int p = 0; p < 4; ++p) {
    const int fg = fbase + p;
    const int bb = fg / NFRAME;
    const int fr = fg - bb * NFRAME;
    const float* xb = x + (size_t)bb * NSAMP;

    // load frame; en partial; write packed FFT input
    float esum = 0.0f;
    #pragma unroll
    for (int q = 0; q < 4; ++q) {
      const int n = tid + q * 256;
      const int g = fr * 256 + n - 512;
      const float xv = (g >= 0 && g < NSAMP) ? xb[g] : 0.0f;
      esum += xv * xv;
      A[n] = make_float2(xv * wv[q] * invn, xv);  // z = xw + i*xf
    }
    esum = waveReduceSum(esum);
    if (lane == 0) sred[w] = esum;
    __syncthreads();
    if (tid == 0) {
      const float en = sred[0] + sred[1] + sred[2] + sred[3];
      out[EN_OFF + fg] = 10.0f * log10f(en + 1e-10f);
    }

    fft1024p(A, Bb, tw, tid);  // packed spectra -> Bb (5 barriers)

    // unpack spectra, Pw[<232], x_ds, centroid partials
    float cs0 = 0.0f, cs1 = 0.0f;
    for (int k = tid; k < 513; k += 256) {
      const float2 Zk = Bb[k];
      const float2 Zn = Bb[(1024 - k) & 1023];
      const float xwr = 0.5f * (Zk.x + Zn.x);
      const float xwi = 0.5f * (Zk.y - Zn.y);
      const float xfr = 0.5f * (Zk.y + Zn.y);
      const float xfi = -0.5f * (Zk.x - Zn.x);
      const float pw = xwr * xwr + xwi * xwi;
      const float pf = xfr * xfr + xfi * xfi;
      const float mg = sqrtf(pf);
      cs0 += mg;
      cs1 += mg * ((float)k * (22050.0f / 1024.0f));
      if (k < 232) {
        Pw[k] = pw;
        if (xds_pf == 232) {
          out[XDS_OFF + (size_t)fg * 232 + k] = xwr;
        } else {
          out[XDS_OFF + (size_t)fg * 464 + 2 * k]     = xwr;
          out[XDS_OFF + (size_t)fg * 464 + 2 * k + 1] = xwi;
        }
      }
    }
    blockReduceSum2(cs0, cs1, sred);   // 2 barriers; also makes Pw visible
    if (tid == 0) out[CEN_OFF + fg] = cs1 / (cs0 + 1e-10f);

    // pack 2nd FFT input, recomputing pw/pf from Bb (bit-identical expressions)
    #pragma unroll
    for (int q = 0; q < 4; ++q) {
      const int k2 = tid + q * 256;
      const int km = (k2 <= 512) ? k2 : (1024 - k2);
      const float2 Zk = Bb[km];
      const float2 Zn = Bb[(1024 - km) & 1023];
      const float xwr = 0.5f * (Zk.x + Zn.x);
      const float xwi = 0.5f * (Zk.y - Zn.y);
      const float xfr = 0.5f * (Zk.y + Zn.y);
      const float xfi = -0.5f * (Zk.x - Zn.x);
      const float pw = xwr * xwr + xwi * xwi;
      const float pf = xfr * xfr + xfi * xfi;
      A[k2] = make_float2(pw * 1024.0f, pf);
    }
    __syncthreads();

    fft1024p(A, Bb, tw, tid);  // Bb[n].x = 2^20*ac_w[n], Bb[n].y = 1024*ac_f[n]

    // pitch: argmax lags 44..441 (first-max tie-break)
    float pv = -3.0e38f;
    int   pl = 1 << 30;
    for (int l = 44 + tid; l <= 441; l += 256) {
      const float v = Bb[l].y;
      if (v > pv) { pv = v; pl = l; }
    }
    #pragma unroll
    for (int m = 1; m < 64; m <<= 1) {
      const float ov = __shfl_xor(pv, m, 64);
      const int   ol = __shfl_xor(pl, m, 64);
      if (ov > pv || (ov == pv && ol < pl)) { pv = ov; pl = ol; }
    }
    if (lane == 0) { sred[w] = pv; sredi[w] = pl; }
    __syncthreads();
    if (tid == 0) {
      float bv = sred[0]; int bl = sredi[0];
      #pragma unroll
      for (int q = 1; q < 4; ++q)
        if (sred[q] > bv || (sred[q] == bv && sredi[q] < bl)) { bv = sred[q]; bl = sredi[q]; }
      const float ac0  = Bb[0].y * (1.0f / 1024.0f);
      const float peak = bv * (1.0f / 1024.0f);
      const float nccf = peak / (ac0 + 1e-9f);
      out[PITCH_OFF + fg] = logf(22050.0f / (float)bl);
      out[VOI_OFF + fg]   = (nccf > 0.3f) ? 1.0f : 0.0f;
      out[nccf_off + fg]  = nccf;
    }

    // acds lags 0..10: per-wave partials, ONE barrier; cross-wave order s0+s1+s2+s3
    const float pwW = (tid < 232) ? Pw[tid] * wgt462 : 0.0f;
    #pragma unroll
    for (int l = 0; l < 11; ++l) {
      const float t = waveReduceSum(pwW * ctab[l]);
      if (lane == 0) aprt[w][l] = t;
    }
    __syncthreads();   // aprt visible (also protects sred/sredi reuse)
    if (tid < 11)
      stash[p][31 + tid] = aprt[0][tid] + aprt[1][tid] + aprt[2][tid] + aprt[3][tid];
    if (tid == 0) {
      const float a0 = aprt[0][0] + aprt[1][0] + aprt[2][0] + aprt[3][0];
      const float a1 = aprt[0][1] + aprt[1][1] + aprt[2][1] + aprt[3][1];
      out[TILT_OFF + fg] = a1 / (a0 + 1e-10f);
    }
    if (tid < 31) stash[p][tid] = Bb[tid].x * (1.0f / 1048576.0f);  // normalized r30
    __syncthreads();   // phase end: stash visible; A/Bb/Pw free
  }

  // ---- deferred tails: wave w -> frame fbase+w, all concurrent, no barriers ----
  {
    const int fg = fbase + w;

    levinson_f30(&stash[w][0],
                 (lane == 0) ? (out + RC_OFF + (size_t)fg * 30) : (float*)nullptr);

    double rds[11], a10[11];
    #pragma unroll
    for (int l = 0; l < 11; ++l) rds[l] = (double)stash[w][31 + l];
    levinson_d<10>(rds, a10);

    // Durand-Kerner in f64: lane i owns root i (i<10), Jacobi update via shfl
    double zr = 0.4, zi = 0.9;
    for (int q = 0; q < lane; ++q) {
      const double nr = zr * 0.4 - zi * 0.9;
      zi = zr * 0.9 + zi * 0.4;
      zr = nr;
    }
    for (int it = 0; it < 60; ++it) {
      double pr = 1.0, pi = 0.0;            // Horner, c[0]=1
      #pragma unroll
      for (int q = 1; q <= 10; ++q) {
        const double nr = pr * zr - pi * zi + a10[q];
        pi = pr * zi + pi * zr;
        pr = nr;
      }
      double dr = 1.0, di = 0.0;
      #pragma unroll
      for (int j = 0; j < 10; ++j) {
        const double ozr = __shfl(zr, j, 64);
        const double ozi = __shfl(zi, j, 64);
        const double er = (j == lane) ? 1.0 : (zr - ozr);
        const double ei = (j == lane) ? 0.0 : (zi - ozi);
        const double nr = dr * er - di * ei;
        di = dr * ei + di * er;
        dr = nr;
      }
      dr += 1e-12;
      const double d2 = dr * dr + di * di;
      const double qr = (pr * dr + pi * di) / d2;
      const double qi = (pi * dr - pr * di) / d2;
      zr -= qr;
      zi -= qi;
    }
    const double ang = atan2(zi, zr);
    double freq = (ang > 0.0001) ? (ang / 6.283185307179586476925287 * 10000.0) : 5000.0;
    if (lane >= 10) freq = 1.0e300;
    double fsel[4];
    #pragma unroll
    for (int p2 = 0; p2 < 4; ++p2) {
      double mn = freq;
      #pragma unroll
      for (int m = 1; m < 64; m <<= 1) mn = fmin(mn, __shfl_xor(mn, m, 64));
      fsel[p2] = mn;
      const unsigned long long bal = __ballot(freq == mn);
      const int low = (int)__builtin_ctzll(bal);
      if (lane == low) freq = 1.0e300;
    }
    if (lane == 0) {
      out[(size_t)fg * 4 + 0] = (float)fsel[0];
      out[(size_t)fg * 4 + 1] = (float)fsel[1];
      out[(size_t)fg * 4 + 2] = (float)fsel[2];
      out[(size_t)fg * 4 + 3] = (float)fsel[3];
    }
  }
}

extern "C" void kernel_launch(void* const* d_in, const int* in_sizes, int n_in,
                              void* d_out, int out_size, void* d_ws, size_t ws_size,
                              hipStream_t stream) {
  (void)in_sizes; (void)n_in; (void)d_ws; (void)ws_size;
  const float* x = (const float*)d_in[0];
  float* out = (float*)d_out;
  int xds_pf = 232;
  if (out_size >= XDS_OFF + NFTOT * 464 + NFTOT) xds_pf = 464;
  const int nccf_off = XDS_OFF + NFTOT * xds_pf;
  feat_mono4<<<dim3(NFTOT / 4), dim3(256), 0, stream>>>(x, out, xds_pf, nccf_off);
}

// Round 10
// 379.105 us; speedup vs baseline: 3.9503x; 1.9916x over previous
//
#include <hip/hip_runtime.h>
#include <math.h>

#define NSAMP   661500
#define NFRAME  2584
#define NFTOT   20672

#define EN_OFF    82688
#define CEN_OFF   103360
#define TILT_OFF  124032
#define PITCH_OFF 144704
#define VOI_OFF   165376
#define RC_OFF    186048
#define XDS_OFF   806208

__device__ __forceinline__ float waveReduceSum(float v) {
  #pragma unroll
  for (int m = 1; m < 64; m <<= 1) v += __shfl_xor(v, m, 64);
  return v;
}

__device__ __forceinline__ float blockReduceSum(float v, float* s) {
  v = waveReduceSum(v);
  const int w = threadIdx.x >> 6;
  if ((threadIdx.x & 63) == 0) s[w] = v;
  __syncthreads();
  v = s[0] + s[1] + s[2] + s[3];
  __syncthreads();
  return v;
}

// two reductions sharing one barrier pair; same per-value add order as blockReduceSum
__device__ __forceinline__ void blockReduceSum2(float& v0, float& v1, float* s) {
  v0 = waveReduceSum(v0);
  v1 = waveReduceSum(v1);
  const int w = threadIdx.x >> 6;
  if ((threadIdx.x & 63) == 0) { s[w] = v0; s[4 + w] = v1; }
  __syncthreads();
  v0 = s[0] + s[1] + s[2] + s[3];
  v1 = s[4] + s[5] + s[6] + s[7];
  __syncthreads();
}

// Stockham radix-2 DIF, N=1024, forward (e^{-i}), TWO stages fused per barrier.
// 5 barriers; result ends in the second buffer.
__device__ __forceinline__ void fft1024p(float2* X, float2* Y, const float2* tw, int tid) {
  int m = 1;
  #pragma unroll
  for (int s = 0; s < 5; ++s) {
    const int k  = tid & (m - 1);
    const int jm = tid - k;
    const float2 a0 = X[tid];
    const float2 a1 = X[tid + 256];
    const float2 a2 = X[tid + 512];
    const float2 a3 = X[tid + 768];
    const float2 w1 = tw[jm];
    float2 sA, dA, sB, dB;
    sA.x = a0.x + a2.x; sA.y = a0.y + a2.y;
    { const float dx = a0.x - a2.x, dy = a0.y - a2.y;
      dA.x = dx * w1.x + dy * w1.y;            // d * conj(w1)
      dA.y = dy * w1.x - dx * w1.y; }
    sB.x = a1.x + a3.x; sB.y = a1.y + a3.y;
    { const float dx = a1.x - a3.x, dy = a1.y - a3.y;
      const float wx = -w1.y, wy = w1.x;       // i * w1
      dB.x = dx * wx + dy * wy;
      dB.y = dy * wx - dx * wy; }
    const float w2x = w1.x * w1.x - w1.y * w1.y;   // w1^2
    const float w2y = 2.0f * w1.x * w1.y;
    const int B = 4 * tid - 3 * k;
    { float2 o;
      o.x = sA.x + sB.x; o.y = sA.y + sB.y;
      Y[B] = o;
      const float dx = sA.x - sB.x, dy = sA.y - sB.y;
      o.x = dx * w2x + dy * w2y;
      o.y = dy * w2x - dx * w2y;
      Y[B + 2 * m] = o; }
    { float2 o;
      o.x = dA.x + dB.x; o.y = dA.y + dB.y;
      Y[B + m] = o;
      const float dx = dA.x - dB.x, dy = dA.y - dB.y;
      o.x = dx * w2x + dy * w2y;
      o.y = dy * w2x - dx * w2y;
      Y[B + 3 * m] = o; }
    __syncthreads();
    float2* tmp = X; X = Y; Y = tmp;
    m <<= 2;
  }
}

// f64 Levinson matching the reference recurrence (order 10 -> DK).
template<int ORDER>
__device__ __forceinline__ void levinson_d(const double* r, double* a) {
  double E = r[0];
  a[0] = 1.0;
  #pragma unroll
  for (int m = 1; m <= ORDER; ++m) {
    double acc = r[m];
    #pragma unroll
    for (int i = 1; i < m; ++i) acc += a[i] * r[m - i];
    const double kk = -acc / (E + 1e-9);
    #pragma unroll
    for (int i = 1; i <= (m - 1) / 2; ++i) {
      const double t1 = a[i], t2 = a[m - i];
      a[i]     = t1 + kk * t2;
      a[m - i] = t2 + kk * t1;
    }
    if ((m & 1) == 0) { const double t = a[m >> 1]; a[m >> 1] = t + kk * t; }
    a[m] = kk;
    E *= (1.0 - kk * kk);
  }
}

// f32 Levinson, order 30, rc out; r read from LDS.
__device__ __forceinline__ void levinson_f30(const float* r, float* gk) {
  float a[31];
  float E = r[0];
  a[0] = 1.0f;
  #pragma unroll
  for (int m = 1; m <= 30; ++m) {
    float acc = r[m];
    #pragma unroll
    for (int i = 1; i < m; ++i) acc += a[i] * r[m - i];
    const float kk = -acc / (E + 1e-9f);
    #pragma unroll
    for (int i = 1; i <= (m - 1) / 2; ++i) {
      const float t1 = a[i], t2 = a[m - i];
      a[i]     = t1 + kk * t2;
      a[m - i] = t2 + kk * t1;
    }
    if ((m & 1) == 0) { const float t = a[m >> 1]; a[m >> 1] = t + kk * t; }
    a[m] = kk;
    E *= (1.0f - kk * kk);
    if (gk) gk[m - 1] = kk;
  }
}

__global__ void __launch_bounds__(256, 6)
feat_mono4(const float* __restrict__ x, float* __restrict__ out,
           const int xds_pf, const int nccf_off) {
  __shared__ float2 A[1024];
  __shared__ float2 Bb[1024];
  __shared__ float2 tw[256];
  __shared__ float  Pw[232];
  __shared__ float  sred[8];
  __shared__ int    sredi[4];
  __shared__ float  stash[4][42];   // [phase][0..30]=r30 (normalized), [31..41]=acds
  __shared__ float  aprt[4][11];

  const int tid   = threadIdx.x;
  const int w     = tid >> 6;
  const int lane  = tid & 63;
  const int fbase = blockIdx.x * 4;

  // ---- per-block prologue (amortized over 4 frames) ----
  {
    const float th = (float)tid * (6.2831853071795864769f / 1024.0f);
    float sn, cn;
    sincosf(th, &sn, &cn);
    tw[tid] = make_float2(cn, sn);
  }
  float wv[4];
  float wsq = 0.0f;
  #pragma unroll
  for (int q = 0; q < 4; ++q) {
    const int n = tid + q * 256;
    const float th = (float)n * (6.2831853071795864769f / 1023.0f);
    const float wn = 0.42f - 0.5f * cosf(th) + 0.08f * cosf(2.0f * th);
    wv[q] = wn;
    wsq += wn * wn;
  }
  float ctab[11];
  #pragma unroll
  for (int l = 0; l < 11; ++l)
    ctab[l] = cosf((float)(tid * l) * (6.2831853071795864769f / 462.0f));
  const float wgt462 = ((tid == 0 || tid == 231) ? 1.0f : 2.0f) * (1.0f / 462.0f);
  __syncthreads();   // tw visible
  const float invn = 1.0f / sqrtf(blockReduceSum(wsq, sred));

  #pragma unroll 1
  for (int p = 0; p < 4; ++p) {
    const int fg = fbase + p;
    const int bb = fg / NFRAME;
    const int fr = fg - bb * NFRAME;
    const float* xb = x + (size_t)bb * NSAMP;

    // load frame; en partial; write packed FFT input
    float esum = 0.0f;
    #pragma unroll
    for (int q = 0; q < 4; ++q) {
      const int n = tid + q * 256;
      const int g = fr * 256 + n - 512;
      const float xv = (g >= 0 && g < NSAMP) ? xb[g] : 0.0f;
      esum += xv * xv;
      A[n] = make_float2(xv * wv[q] * invn, xv);  // z = xw + i*xf
    }
    esum = waveReduceSum(esum);
    if (lane == 0) sred[w] = esum;
    __syncthreads();
    if (tid == 0) {
      const float en = sred[0] + sred[1] + sred[2] + sred[3];
      out[EN_OFF + fg] = 10.0f * log10f(en + 1e-10f);
    }

    fft1024p(A, Bb, tw, tid);  // packed spectra -> Bb (5 barriers)

    // unpack spectra, Pw[<232], x_ds, centroid partials
    float cs0 = 0.0f, cs1 = 0.0f;
    for (int k = tid; k < 513; k += 256) {
      const float2 Zk = Bb[k];
      const float2 Zn = Bb[(1024 - k) & 1023];
      const float xwr = 0.5f * (Zk.x + Zn.x);
      const float xwi = 0.5f * (Zk.y - Zn.y);
      const float xfr = 0.5f * (Zk.y + Zn.y);
      const float xfi = -0.5f * (Zk.x - Zn.x);
      const float pw = xwr * xwr + xwi * xwi;
      const float pf = xfr * xfr + xfi * xfi;
      const float mg = sqrtf(pf);
      cs0 += mg;
      cs1 += mg * ((float)k * (22050.0f / 1024.0f));
      if (k < 232) {
        Pw[k] = pw;
        if (xds_pf == 232) {
          out[XDS_OFF + (size_t)fg * 232 + k] = xwr;
        } else {
          out[XDS_OFF + (size_t)fg * 464 + 2 * k]     = xwr;
          out[XDS_OFF + (size_t)fg * 464 + 2 * k + 1] = xwi;
        }
      }
    }
    blockReduceSum2(cs0, cs1, sred);   // 2 barriers; also makes Pw visible
    if (tid == 0) out[CEN_OFF + fg] = cs1 / (cs0 + 1e-10f);

    // pack 2nd FFT input, recomputing pw/pf from Bb (bit-identical expressions)
    #pragma unroll
    for (int q = 0; q < 4; ++q) {
      const int k2 = tid + q * 256;
      const int km = (k2 <= 512) ? k2 : (1024 - k2);
      const float2 Zk = Bb[km];
      const float2 Zn = Bb[(1024 - km) & 1023];
      const float xwr = 0.5f * (Zk.x + Zn.x);
      const float xwi = 0.5f * (Zk.y - Zn.y);
      const float xfr = 0.5f * (Zk.y + Zn.y);
      const float xfi = -0.5f * (Zk.x - Zn.x);
      const float pw = xwr * xwr + xwi * xwi;
      const float pf = xfr * xfr + xfi * xfi;
      A[k2] = make_float2(pw * 1024.0f, pf);
    }
    __syncthreads();

    fft1024p(A, Bb, tw, tid);  // Bb[n].x = 2^20*ac_w[n], Bb[n].y = 1024*ac_f[n]

    // pitch: argmax lags 44..441 (first-max tie-break)
    float pv = -3.0e38f;
    int   pl = 1 << 30;
    for (int l = 44 + tid; l <= 441; l += 256) {
      const float v = Bb[l].y;
      if (v > pv) { pv = v; pl = l; }
    }
    #pragma unroll
    for (int m = 1; m < 64; m <<= 1) {
      const float ov = __shfl_xor(pv, m, 64);
      const int   ol = __shfl_xor(pl, m, 64);
      if (ov > pv || (ov == pv && ol < pl)) { pv = ov; pl = ol; }
    }
    if (lane == 0) { sred[w] = pv; sredi[w] = pl; }
    __syncthreads();
    if (tid == 0) {
      float bv = sred[0]; int bl = sredi[0];
      #pragma unroll
      for (int q = 1; q < 4; ++q)
        if (sred[q] > bv || (sred[q] == bv && sredi[q] < bl)) { bv = sred[q]; bl = sredi[q]; }
      const float ac0  = Bb[0].y * (1.0f / 1024.0f);
      const float peak = bv * (1.0f / 1024.0f);
      const float nccf = peak / (ac0 + 1e-9f);
      out[PITCH_OFF + fg] = logf(22050.0f / (float)bl);
      out[VOI_OFF + fg]   = (nccf > 0.3f) ? 1.0f : 0.0f;
      out[nccf_off + fg]  = nccf;
    }

    // acds lags 0..10: per-wave partials, ONE barrier; cross-wave order s0+s1+s2+s3
    const float pwW = (tid < 232) ? Pw[tid] * wgt462 : 0.0f;
    #pragma unroll
    for (int l = 0; l < 11; ++l) {
      const float t = waveReduceSum(pwW * ctab[l]);
      if (lane == 0) aprt[w][l] = t;
    }
    __syncthreads();   // aprt visible (also protects sred/sredi reuse)
    if (tid < 11)
      stash[p][31 + tid] = aprt[0][tid] + aprt[1][tid] + aprt[2][tid] + aprt[3][tid];
    if (tid == 0) {
      const float a0 = aprt[0][0] + aprt[1][0] + aprt[2][0] + aprt[3][0];
      const float a1 = aprt[0][1] + aprt[1][1] + aprt[2][1] + aprt[3][1];
      out[TILT_OFF + fg] = a1 / (a0 + 1e-10f);
    }
    if (tid < 31) stash[p][tid] = Bb[tid].x * (1.0f / 1048576.0f);  // normalized r30
    __syncthreads();   // phase end: stash visible to all; A/Bb/Pw free
  }

  // ---- deferred tails: ALL FOUR frames packed into wave 0 (4 x 16-lane groups);
  //      waves 1-3 exit. Per-group math bit-identical to the 1-frame-per-wave form.
  if (w == 0) {
    const int g     = lane >> 4;     // frame group 0..3
    const int ri    = lane & 15;     // root index within group (0..9 used)
    const int gbase = g << 4;
    const int fg    = fbase + g;

    levinson_f30(&stash[g][0],
                 (ri == 0) ? (out + RC_OFF + (size_t)fg * 30) : (float*)nullptr);

    double rds[11], a10[11];
    #pragma unroll
    for (int l = 0; l < 11; ++l) rds[l] = (double)stash[g][31 + l];
    levinson_d<10>(rds, a10);

    // Durand-Kerner in f64: group lane ri owns root ri; Jacobi via shfl in-group
    double zr = 0.4, zi = 0.9;
    for (int q = 0; q < ri; ++q) {
      const double nr = zr * 0.4 - zi * 0.9;
      zi = zr * 0.9 + zi * 0.4;
      zr = nr;
    }
    for (int it = 0; it < 60; ++it) {
      double pr = 1.0, pi = 0.0;            // Horner, c[0]=1
      #pragma unroll
      for (int q = 1; q <= 10; ++q) {
        const double nr = pr * zr - pi * zi + a10[q];
        pi = pr * zi + pi * zr;
        pr = nr;
      }
      double dr = 1.0, di = 0.0;
      #pragma unroll
      for (int j = 0; j < 10; ++j) {
        const double ozr = __shfl(zr, gbase + j, 64);
        const double ozi = __shfl(zi, gbase + j, 64);
        const double er = (j == ri) ? 1.0 : (zr - ozr);
        const double ei = (j == ri) ? 0.0 : (zi - ozi);
        const double nr = dr * er - di * ei;
        di = dr * ei + di * er;
        dr = nr;
      }
      dr += 1e-12;
      const double d2 = dr * dr + di * di;
      const double qr = (pr * dr + pi * di) / d2;
      const double qi = (pi * dr - pr * di) / d2;
      zr -= qr;
      zi -= qi;
    }
    const double ang = atan2(zi, zr);
    double freq = (ang > 0.0001) ? (ang / 6.283185307179586476925287 * 10000.0) : 5000.0;
    if (ri >= 10) freq = 1.0e300;
    double fsel[4];
    #pragma unroll
    for (int p2 = 0; p2 < 4; ++p2) {
      double mn = freq;
      #pragma unroll
      for (int m = 1; m < 16; m <<= 1) mn = fmin(mn, __shfl_xor(mn, m, 64));
      fsel[p2] = mn;
      const unsigned long long bal =
          __ballot(freq == mn) & (0xFFFFULL << gbase);
      const int low = (int)__builtin_ctzll(bal);
      if (lane == low) freq = 1.0e300;
    }
    if (ri == 0) {
      out[(size_t)fg * 4 + 0] = (float)fsel[0];
      out[(size_t)fg * 4 + 1] = (float)fsel[1];
      out[(size_t)fg * 4 + 2] = (float)fsel[2];
      out[(size_t)fg * 4 + 3] = (float)fsel[3];
    }
  }
}

extern "C" void kernel_launch(void* const* d_in, const int* in_sizes, int n_in,
                              void* d_out, int out_size, void* d_ws, size_t ws_size,
                              hipStream_t stream) {
  (void)in_sizes; (void)n_in; (void)d_ws; (void)ws_size;
  const float* x = (const float*)d_in[0];
  float* out = (float*)d_out;
  int xds_pf = 232;
  if (out_size >= XDS_OFF + NFTOT * 464 + NFTOT) xds_pf = 464;
  const int nccf_off = XDS_OFF + NFTOT * xds_pf;
  feat_mono4<<<dim3(NFTOT / 4), dim3(256), 0, stream>>>(x, out, xds_pf, nccf_off);
}

// Round 11
// 337.354 us; speedup vs baseline: 4.4392x; 1.1238x over previous
//
#include <hip/hip_runtime.h>
#include <math.h>

#define NSAMP   661500
#define NFRAME  2584
#define NFTOT   20672
#define FPB     6
#define NBLK    3446          // ceil(20672/6); last block handles 2 frames

#define EN_OFF    82688
#define CEN_OFF   103360
#define TILT_OFF  124032
#define PITCH_OFF 144704
#define VOI_OFF   165376
#define RC_OFF    186048
#define XDS_OFF   806208

__device__ __forceinline__ float waveReduceSum(float v) {
  #pragma unroll
  for (int m = 1; m < 64; m <<= 1) v += __shfl_xor(v, m, 64);
  return v;
}

__device__ __forceinline__ float blockReduceSum(float v, float* s) {
  v = waveReduceSum(v);
  const int w = threadIdx.x >> 6;
  if ((threadIdx.x & 63) == 0) s[w] = v;
  __syncthreads();
  v = s[0] + s[1] + s[2] + s[3];
  __syncthreads();
  return v;
}

// two reductions sharing one barrier pair; same per-value add order as blockReduceSum
__device__ __forceinline__ void blockReduceSum2(float& v0, float& v1, float* s) {
  v0 = waveReduceSum(v0);
  v1 = waveReduceSum(v1);
  const int w = threadIdx.x >> 6;
  if ((threadIdx.x & 63) == 0) { s[w] = v0; s[4 + w] = v1; }
  __syncthreads();
  v0 = s[0] + s[1] + s[2] + s[3];
  v1 = s[4] + s[5] + s[6] + s[7];
  __syncthreads();
}

// Stockham radix-2 DIF, N=1024, forward (e^{-i}), TWO stages fused per barrier.
// 5 barriers; result ends in the second buffer.
__device__ __forceinline__ void fft1024p(float2* X, float2* Y, const float2* tw, int tid) {
  int m = 1;
  #pragma unroll
  for (int s = 0; s < 5; ++s) {
    const int k  = tid & (m - 1);
    const int jm = tid - k;
    const float2 a0 = X[tid];
    const float2 a1 = X[tid + 256];
    const float2 a2 = X[tid + 512];
    const float2 a3 = X[tid + 768];
    const float2 w1 = tw[jm];
    float2 sA, dA, sB, dB;
    sA.x = a0.x + a2.x; sA.y = a0.y + a2.y;
    { const float dx = a0.x - a2.x, dy = a0.y - a2.y;
      dA.x = dx * w1.x + dy * w1.y;            // d * conj(w1)
      dA.y = dy * w1.x - dx * w1.y; }
    sB.x = a1.x + a3.x; sB.y = a1.y + a3.y;
    { const float dx = a1.x - a3.x, dy = a1.y - a3.y;
      const float wx = -w1.y, wy = w1.x;       // i * w1
      dB.x = dx * wx + dy * wy;
      dB.y = dy * wx - dx * wy; }
    const float w2x = w1.x * w1.x - w1.y * w1.y;   // w1^2
    const float w2y = 2.0f * w1.x * w1.y;
    const int B = 4 * tid - 3 * k;
    { float2 o;
      o.x = sA.x + sB.x; o.y = sA.y + sB.y;
      Y[B] = o;
      const float dx = sA.x - sB.x, dy = sA.y - sB.y;
      o.x = dx * w2x + dy * w2y;
      o.y = dy * w2x - dx * w2y;
      Y[B + 2 * m] = o; }
    { float2 o;
      o.x = dA.x + dB.x; o.y = dA.y + dB.y;
      Y[B + m] = o;
      const float dx = dA.x - dB.x, dy = dA.y - dB.y;
      o.x = dx * w2x + dy * w2y;
      o.y = dy * w2x - dx * w2y;
      Y[B + 3 * m] = o; }
    __syncthreads();
    float2* tmp = X; X = Y; Y = tmp;
    m <<= 2;
  }
}

// f64 Levinson matching the reference recurrence (order 10 -> DK).
template<int ORDER>
__device__ __forceinline__ void levinson_d(const double* r, double* a) {
  double E = r[0];
  a[0] = 1.0;
  #pragma unroll
  for (int m = 1; m <= ORDER; ++m) {
    double acc = r[m];
    #pragma unroll
    for (int i = 1; i < m; ++i) acc += a[i] * r[m - i];
    const double kk = -acc / (E + 1e-9);
    #pragma unroll
    for (int i = 1; i <= (m - 1) / 2; ++i) {
      const double t1 = a[i], t2 = a[m - i];
      a[i]     = t1 + kk * t2;
      a[m - i] = t2 + kk * t1;
    }
    if ((m & 1) == 0) { const double t = a[m >> 1]; a[m >> 1] = t + kk * t; }
    a[m] = kk;
    E *= (1.0 - kk * kk);
  }
}

// f32 Levinson, order 30, rc out; r read from LDS.
__device__ __forceinline__ void levinson_f30(const float* r, float* gk) {
  float a[31];
  float E = r[0];
  a[0] = 1.0f;
  #pragma unroll
  for (int m = 1; m <= 30; ++m) {
    float acc = r[m];
    #pragma unroll
    for (int i = 1; i < m; ++i) acc += a[i] * r[m - i];
    const float kk = -acc / (E + 1e-9f);
    #pragma unroll
    for (int i = 1; i <= (m - 1) / 2; ++i) {
      const float t1 = a[i], t2 = a[m - i];
      a[i]     = t1 + kk * t2;
      a[m - i] = t2 + kk * t1;
    }
    if ((m & 1) == 0) { const float t = a[m >> 1]; a[m >> 1] = t + kk * t; }
    a[m] = kk;
    E *= (1.0f - kk * kk);
    if (gk) gk[m - 1] = kk;
  }
}

__global__ void __launch_bounds__(256, 7)
feat_mono6(const float* __restrict__ x, float* __restrict__ out,
           const int xds_pf, const int nccf_off) {
  __shared__ float2 A[1024];
  __shared__ float2 Bb[1024];
  __shared__ float2 tw[256];
  __shared__ float  Pw[232];
  __shared__ float  sred[8];
  __shared__ int    sredi[4];
  __shared__ float  stash[FPB][42];  // [phase][0..30]=r30 (normalized), [31..41]=acds
  __shared__ float  aprt[4][11];

  const int tid   = threadIdx.x;
  const int w     = tid >> 6;
  const int lane  = tid & 63;
  const int fbase = blockIdx.x * FPB;
  const int np    = (fbase + FPB <= NFTOT) ? FPB : (NFTOT - fbase);

  // ---- per-block prologue (amortized over FPB frames) ----
  {
    const float th = (float)tid * (6.2831853071795864769f / 1024.0f);
    float sn, cn;
    sincosf(th, &sn, &cn);
    tw[tid] = make_float2(cn, sn);
  }
  float wv[4];
  float wsq = 0.0f;
  #pragma unroll
  for (int q = 0; q < 4; ++q) {
    const int n = tid + q * 256;
    const float th = (float)n * (6.2831853071795864769f / 1023.0f);
    const float wn = 0.42f - 0.5f * cosf(th) + 0.08f * cosf(2.0f * th);
    wv[q] = wn;
    wsq += wn * wn;
  }
  float ctab[11];
  #pragma unroll
  for (int l = 0; l < 11; ++l)
    ctab[l] = cosf((float)(tid * l) * (6.2831853071795864769f / 462.0f));
  const float wgt462 = ((tid == 0 || tid == 231) ? 1.0f : 2.0f) * (1.0f / 462.0f);
  __syncthreads();   // tw visible
  const float invn = 1.0f / sqrtf(blockReduceSum(wsq, sred));

  #pragma unroll 1
  for (int p = 0; p < np; ++p) {
    const int fg = fbase + p;
    const int bb = fg / NFRAME;
    const int fr = fg - bb * NFRAME;
    const float* xb = x + (size_t)bb * NSAMP;

    // load frame; en partial; write packed FFT input
    float esum = 0.0f;
    #pragma unroll
    for (int q = 0; q < 4; ++q) {
      const int n = tid + q * 256;
      const int g = fr * 256 + n - 512;
      const float xv = (g >= 0 && g < NSAMP) ? xb[g] : 0.0f;
      esum += xv * xv;
      A[n] = make_float2(xv * wv[q] * invn, xv);  // z = xw + i*xf
    }
    esum = waveReduceSum(esum);
    if (lane == 0) sred[w] = esum;
    __syncthreads();
    if (tid == 0) {
      const float en = sred[0] + sred[1] + sred[2] + sred[3];
      out[EN_OFF + fg] = 10.0f * log10f(en + 1e-10f);
    }

    fft1024p(A, Bb, tw, tid);  // packed spectra -> Bb (5 barriers)

    // unpack spectra, Pw[<232], x_ds, centroid partials
    float cs0 = 0.0f, cs1 = 0.0f;
    for (int k = tid; k < 513; k += 256) {
      const float2 Zk = Bb[k];
      const float2 Zn = Bb[(1024 - k) & 1023];
      const float xwr = 0.5f * (Zk.x + Zn.x);
      const float xwi = 0.5f * (Zk.y - Zn.y);
      const float xfr = 0.5f * (Zk.y + Zn.y);
      const float xfi = -0.5f * (Zk.x - Zn.x);
      const float pw = xwr * xwr + xwi * xwi;
      const float pf = xfr * xfr + xfi * xfi;
      const float mg = sqrtf(pf);
      cs0 += mg;
      cs1 += mg * ((float)k * (22050.0f / 1024.0f));
      if (k < 232) {
        Pw[k] = pw;
        if (xds_pf == 232) {
          out[XDS_OFF + (size_t)fg * 232 + k] = xwr;
        } else {
          out[XDS_OFF + (size_t)fg * 464 + 2 * k]     = xwr;
          out[XDS_OFF + (size_t)fg * 464 + 2 * k + 1] = xwi;
        }
      }
    }
    blockReduceSum2(cs0, cs1, sred);   // 2 barriers; also makes Pw visible
    if (tid == 0) out[CEN_OFF + fg] = cs1 / (cs0 + 1e-10f);

    // pack 2nd FFT input, recomputing pw/pf from Bb (bit-identical expressions)
    #pragma unroll
    for (int q = 0; q < 4; ++q) {
      const int k2 = tid + q * 256;
      const int km = (k2 <= 512) ? k2 : (1024 - k2);
      const float2 Zk = Bb[km];
      const float2 Zn = Bb[(1024 - km) & 1023];
      const float xwr = 0.5f * (Zk.x + Zn.x);
      const float xwi = 0.5f * (Zk.y - Zn.y);
      const float xfr = 0.5f * (Zk.y + Zn.y);
      const float xfi = -0.5f * (Zk.x - Zn.x);
      const float pw = xwr * xwr + xwi * xwi;
      const float pf = xfr * xfr + xfi * xfi;
      A[k2] = make_float2(pw * 1024.0f, pf);
    }
    __syncthreads();

    fft1024p(A, Bb, tw, tid);  // Bb[n].x = 2^20*ac_w[n], Bb[n].y = 1024*ac_f[n]

    // pitch: argmax lags 44..441 (first-max tie-break)
    float pv = -3.0e38f;
    int   pl = 1 << 30;
    for (int l = 44 + tid; l <= 441; l += 256) {
      const float v = Bb[l].y;
      if (v > pv) { pv = v; pl = l; }
    }
    #pragma unroll
    for (int m = 1; m < 64; m <<= 1) {
      const float ov = __shfl_xor(pv, m, 64);
      const int   ol = __shfl_xor(pl, m, 64);
      if (ov > pv || (ov == pv && ol < pl)) { pv = ov; pl = ol; }
    }
    if (lane == 0) { sred[w] = pv; sredi[w] = pl; }
    __syncthreads();
    if (tid == 0) {
      float bv = sred[0]; int bl = sredi[0];
      #pragma unroll
      for (int q = 1; q < 4; ++q)
        if (sred[q] > bv || (sred[q] == bv && sredi[q] < bl)) { bv = sred[q]; bl = sredi[q]; }
      const float ac0  = Bb[0].y * (1.0f / 1024.0f);
      const float peak = bv * (1.0f / 1024.0f);
      const float nccf = peak / (ac0 + 1e-9f);
      out[PITCH_OFF + fg] = logf(22050.0f / (float)bl);
      out[VOI_OFF + fg]   = (nccf > 0.3f) ? 1.0f : 0.0f;
      out[nccf_off + fg]  = nccf;
    }

    // acds lags 0..10: per-wave partials, ONE barrier; cross-wave order s0+s1+s2+s3
    const float pwW = (tid < 232) ? Pw[tid] * wgt462 : 0.0f;
    #pragma unroll
    for (int l = 0; l < 11; ++l) {
      const float t = waveReduceSum(pwW * ctab[l]);
      if (lane == 0) aprt[w][l] = t;
    }
    __syncthreads();   // aprt visible (also protects sred/sredi reuse)
    if (tid < 11)
      stash[p][31 + tid] = aprt[0][tid] + aprt[1][tid] + aprt[2][tid] + aprt[3][tid];
    if (tid == 0) {
      const float a0 = aprt[0][0] + aprt[1][0] + aprt[2][0] + aprt[3][0];
      const float a1 = aprt[0][1] + aprt[1][1] + aprt[2][1] + aprt[3][1];
      out[TILT_OFF + fg] = a1 / (a0 + 1e-10f);
    }
    if (tid < 31) stash[p][tid] = Bb[tid].x * (1.0f / 1048576.0f);  // normalized r30
    __syncthreads();   // phase end: stash visible to all; A/Bb/Pw free
  }

  // ---- deferred tails: up to SIX frames packed into wave 0 (6 x 10-lane groups);
  //      waves 1-3 exit. Per-group math bit-identical to the per-wave form.
  if (w == 0) {
    const int g     = lane / 10;            // 0..6 (g=6: lanes 60-63, always inactive)
    const int ri    = lane - g * 10;        // 0..9
    const int gbase = g * 10;
    const int gg    = (g < FPB) ? g : (FPB - 1);   // clamp for safe LDS reads
    const bool act  = (g < np);
    const int fg    = fbase + gg;

    levinson_f30(&stash[gg][0],
                 (ri == 0 && act) ? (out + RC_OFF + (size_t)fg * 30) : (float*)nullptr);

    double rds[11], a10[11];
    #pragma unroll
    for (int l = 0; l < 11; ++l) rds[l] = (double)stash[gg][31 + l];
    levinson_d<10>(rds, a10);

    // Durand-Kerner in f64: group lane ri owns root ri; Jacobi via shfl in-group
    double zr = 0.4, zi = 0.9;
    for (int q = 0; q < ri; ++q) {
      const double nr = zr * 0.4 - zi * 0.9;
      zi = zr * 0.9 + zi * 0.4;
      zr = nr;
    }
    for (int it = 0; it < 60; ++it) {
      double pr = 1.0, pi = 0.0;            // Horner, c[0]=1
      #pragma unroll
      for (int q = 1; q <= 10; ++q) {
        const double nr = pr * zr - pi * zi + a10[q];
        pi = pr * zi + pi * zr;
        pr = nr;
      }
      double dr = 1.0, di = 0.0;
      #pragma unroll
      for (int j = 0; j < 10; ++j) {
        const double ozr = __shfl(zr, gbase + j, 64);
        const double ozi = __shfl(zi, gbase + j, 64);
        const double er = (j == ri) ? 1.0 : (zr - ozr);
        const double ei = (j == ri) ? 0.0 : (zi - ozi);
        const double nr = dr * er - di * ei;
        di = dr * ei + di * er;
        dr = nr;
      }
      dr += 1e-12;
      const double inv = 1.0 / (dr * dr + di * di);   // one divide, two mults
      const double qr = (pr * dr + pi * di) * inv;
      const double qi = (pi * dr - pr * di) * inv;
      zr -= qr;
      zi -= qi;
    }
    const double ang = atan2(zi, zr);
    double freq = (ang > 0.0001) ? (ang / 6.283185307179586476925287 * 10000.0) : 5000.0;
    if (ri >= 10) freq = 1.0e300;

    // gather all 10 freqs of the group, then stable 4-min select (lowest j on ties)
    double f[10];
    #pragma unroll
    for (int j = 0; j < 10; ++j) f[j] = __shfl(freq, gbase + j, 64);
    bool used[10];
    #pragma unroll
    for (int j = 0; j < 10; ++j) used[j] = false;
    float o4[4];
    #pragma unroll
    for (int p2 = 0; p2 < 4; ++p2) {
      double mn = 1.0e300;
      int mj = -1;
      #pragma unroll
      for (int j = 0; j < 10; ++j)
        if (!used[j] && f[j] < mn) { mn = f[j]; mj = j; }
      if (mj >= 0) used[mj] = true;
      o4[p2] = (float)mn;
    }
    if (ri == 0 && act) {
      out[(size_t)fg * 4 + 0] = o4[0];
      out[(size_t)fg * 4 + 1] = o4[1];
      out[(size_t)fg * 4 + 2] = o4[2];
      out[(size_t)fg * 4 + 3] = o4[3];
    }
  }
}

extern "C" void kernel_launch(void* const* d_in, const int* in_sizes, int n_in,
                              void* d_out, int out_size, void* d_ws, size_t ws_size,
                              hipStream_t stream) {
  (void)in_sizes; (void)n_in; (void)d_ws; (void)ws_size;
  const float* x = (const float*)d_in[0];
  float* out = (float*)d_out;
  int xds_pf = 232;
  if (out_size >= XDS_OFF + NFTOT * 464 + NFTOT) xds_pf = 464;
  const int nccf_off = XDS_OFF + NFTOT * xds_pf;
  feat_mono6<<<dim3(NBLK), dim3(256), 0, stream>>>(x, out, xds_pf, nccf_off);
}

// Round 12
// 332.357 us; speedup vs baseline: 4.5060x; 1.0150x over previous
//
#include <hip/hip_runtime.h>
#include <math.h>

#define NSAMP   661500
#define NFRAME  2584
#define NFTOT   20672
#define FPB     6
#define NBLK    3446          // ceil(20672/6); last block handles 2 frames

#define EN_OFF    82688
#define CEN_OFF   103360
#define TILT_OFF  124032
#define PITCH_OFF 144704
#define VOI_OFF   165376
#define RC_OFF    186048
#define XDS_OFF   806208

__device__ __forceinline__ float waveReduceSum(float v) {
  #pragma unroll
  for (int m = 1; m < 64; m <<= 1) v += __shfl_xor(v, m, 64);
  return v;
}

__device__ __forceinline__ float blockReduceSum(float v, float* s) {
  v = waveReduceSum(v);
  const int w = threadIdx.x >> 6;
  if ((threadIdx.x & 63) == 0) s[w] = v;
  __syncthreads();
  v = s[0] + s[1] + s[2] + s[3];
  __syncthreads();
  return v;
}

// Stockham radix-2 DIF, N=1024, forward (e^{-i}), TWO stages fused per barrier.
// 5 barriers; result ends in the second buffer. Requires X visible on entry.
__device__ __forceinline__ void fft1024p(float2* X, float2* Y, const float2* tw, int tid) {
  int m = 1;
  #pragma unroll
  for (int s = 0; s < 5; ++s) {
    const int k  = tid & (m - 1);
    const int jm = tid - k;
    const float2 a0 = X[tid];
    const float2 a1 = X[tid + 256];
    const float2 a2 = X[tid + 512];
    const float2 a3 = X[tid + 768];
    const float2 w1 = tw[jm];
    float2 sA, dA, sB, dB;
    sA.x = a0.x + a2.x; sA.y = a0.y + a2.y;
    { const float dx = a0.x - a2.x, dy = a0.y - a2.y;
      dA.x = dx * w1.x + dy * w1.y;            // d * conj(w1)
      dA.y = dy * w1.x - dx * w1.y; }
    sB.x = a1.x + a3.x; sB.y = a1.y + a3.y;
    { const float dx = a1.x - a3.x, dy = a1.y - a3.y;
      const float wx = -w1.y, wy = w1.x;       // i * w1
      dB.x = dx * wx + dy * wy;
      dB.y = dy * wx - dx * wy; }
    const float w2x = w1.x * w1.x - w1.y * w1.y;   // w1^2
    const float w2y = 2.0f * w1.x * w1.y;
    const int B = 4 * tid - 3 * k;
    { float2 o;
      o.x = sA.x + sB.x; o.y = sA.y + sB.y;
      Y[B] = o;
      const float dx = sA.x - sB.x, dy = sA.y - sB.y;
      o.x = dx * w2x + dy * w2y;
      o.y = dy * w2x - dx * w2y;
      Y[B + 2 * m] = o; }
    { float2 o;
      o.x = dA.x + dB.x; o.y = dA.y + dB.y;
      Y[B + m] = o;
      const float dx = dA.x - dB.x, dy = dA.y - dB.y;
      o.x = dx * w2x + dy * w2y;
      o.y = dy * w2x - dx * w2y;
      Y[B + 3 * m] = o; }
    __syncthreads();
    float2* tmp = X; X = Y; Y = tmp;
    m <<= 2;
  }
}

// f64 Levinson matching the reference recurrence (order 10 -> DK).
template<int ORDER>
__device__ __forceinline__ void levinson_d(const double* r, double* a) {
  double E = r[0];
  a[0] = 1.0;
  #pragma unroll
  for (int m = 1; m <= ORDER; ++m) {
    double acc = r[m];
    #pragma unroll
    for (int i = 1; i < m; ++i) acc += a[i] * r[m - i];
    const double kk = -acc / (E + 1e-9);
    #pragma unroll
    for (int i = 1; i <= (m - 1) / 2; ++i) {
      const double t1 = a[i], t2 = a[m - i];
      a[i]     = t1 + kk * t2;
      a[m - i] = t2 + kk * t1;
    }
    if ((m & 1) == 0) { const double t = a[m >> 1]; a[m >> 1] = t + kk * t; }
    a[m] = kk;
    E *= (1.0 - kk * kk);
  }
}

// f32 Levinson, order 30, rc out; r read from LDS.
__device__ __forceinline__ void levinson_f30(const float* r, float* gk) {
  float a[31];
  float E = r[0];
  a[0] = 1.0f;
  #pragma unroll
  for (int m = 1; m <= 30; ++m) {
    float acc = r[m];
    #pragma unroll
    for (int i = 1; i < m; ++i) acc += a[i] * r[m - i];
    const float kk = -acc / (E + 1e-9f);
    #pragma unroll
    for (int i = 1; i <= (m - 1) / 2; ++i) {
      const float t1 = a[i], t2 = a[m - i];
      a[i]     = t1 + kk * t2;
      a[m - i] = t2 + kk * t1;
    }
    if ((m & 1) == 0) { const float t = a[m >> 1]; a[m >> 1] = t + kk * t; }
    a[m] = kk;
    E *= (1.0f - kk * kk);
    if (gk) gk[m - 1] = kk;
  }
}

__global__ void __launch_bounds__(256, 8)
feat_mono6(const float* __restrict__ x, float* __restrict__ out,
           const int xds_pf, const int nccf_off) {
  __shared__ float2 A[1024];
  __shared__ float2 Bb[1024];
  __shared__ float2 tw[256];
  __shared__ float  sred[12];      // [0..3] pitch pv | [4..7] cs0 | [8..11] cs1
  __shared__ int    sredi[4];
  __shared__ float  stash[FPB][42];  // [phase][0..30]=r30 (normalized), [31..41]=acds
  __shared__ float  aprt[4][11];

  const int tid   = threadIdx.x;
  const int w     = tid >> 6;
  const int lane  = tid & 63;
  const int fbase = blockIdx.x * FPB;
  const int np    = (fbase + FPB <= NFTOT) ? FPB : (NFTOT - fbase);

  // ---- per-block prologue (amortized over FPB frames) ----
  {
    const float th = (float)tid * (6.2831853071795864769f / 1024.0f);
    float sn, cn;
    sincosf(th, &sn, &cn);
    tw[tid] = make_float2(cn, sn);
  }
  float wv[4];
  float wsq = 0.0f;
  #pragma unroll
  for (int q = 0; q < 4; ++q) {
    const int n = tid + q * 256;
    const float th = (float)n * (6.2831853071795864769f / 1023.0f);
    const float wn = 0.42f - 0.5f * cosf(th) + 0.08f * cosf(2.0f * th);
    wv[q] = wn;
    wsq += wn * wn;
  }
  float ctab[11];
  #pragma unroll
  for (int l = 0; l < 11; ++l)
    ctab[l] = cosf((float)(tid * l) * (6.2831853071795864769f / 462.0f));
  const float wgt462 = ((tid == 0 || tid == 231) ? 1.0f : 2.0f) * (1.0f / 462.0f);
  __syncthreads();   // tw visible
  const float invn = 1.0f / sqrtf(blockReduceSum(wsq, sred));

  #pragma unroll 1
  for (int p = 0; p < np; ++p) {
    const int fg = fbase + p;
    const int bb = fg / NFRAME;
    const int fr = fg - bb * NFRAME;
    const float* xb = x + (size_t)bb * NSAMP;

    // load frame; write packed FFT input (no energy pass — Parseval later)
    #pragma unroll
    for (int q = 0; q < 4; ++q) {
      const int n = tid + q * 256;
      const int g = fr * 256 + n - 512;
      const float xv = (g >= 0 && g < NSAMP) ? xb[g] : 0.0f;
      A[n] = make_float2(xv * wv[q] * invn, xv);  // z = xw + i*xf
    }
    __syncthreads();           // A ready (also: prior phase's Bb reads all done)

    fft1024p(A, Bb, tw, tid);  // packed spectra -> Bb (5 barriers)

    // unpack: x_ds, centroid partials, own-acds weight (k=tid) — reads Bb only
    float cs0 = 0.0f, cs1 = 0.0f;
    float myPw = 0.0f;
    {
      const int k = tid;
      const float2 Zk = Bb[k];
      const float2 Zn = Bb[(1024 - k) & 1023];
      const float xwr = 0.5f * (Zk.x + Zn.x);
      const float xwi = 0.5f * (Zk.y - Zn.y);
      const float xfr = 0.5f * (Zk.y + Zn.y);
      const float xfi = -0.5f * (Zk.x - Zn.x);
      const float pw = xwr * xwr + xwi * xwi;
      const float pf = xfr * xfr + xfi * xfi;
      const float mg = sqrtf(pf);
      cs0 += mg;
      cs1 += mg * ((float)k * (22050.0f / 1024.0f));
      if (k < 232) {
        myPw = pw;
        if (xds_pf == 232) {
          out[XDS_OFF + (size_t)fg * 232 + k] = xwr;
        } else {
          ((float2*)(out + XDS_OFF))[(size_t)fg * 232 + k] = make_float2(xwr, xwi);
        }
      }
    }
    {
      const int k = tid + 256;
      const float2 Zk = Bb[k];
      const float2 Zn = Bb[1024 - k];
      const float xfr = 0.5f * (Zk.y + Zn.y);
      const float xfi = -0.5f * (Zk.x - Zn.x);
      const float pf = xfr * xfr + xfi * xfi;
      const float mg = sqrtf(pf);
      cs0 += mg;
      cs1 += mg * ((float)k * (22050.0f / 1024.0f));
    }
    if (tid == 0) {
      const int k = 512;
      const float2 Zk = Bb[k];
      const float2 Zn = Bb[512];
      const float xfr = 0.5f * (Zk.y + Zn.y);
      const float xfi = -0.5f * (Zk.x - Zn.x);
      const float pf = xfr * xfr + xfi * xfi;
      const float mg = sqrtf(pf);
      cs0 += mg;
      cs1 += mg * ((float)k * (22050.0f / 1024.0f));
    }

    // pack 2nd FFT input (reads Bb, writes A — no barrier needed vs unpack)
    #pragma unroll
    for (int q = 0; q < 4; ++q) {
      const int k2 = tid + q * 256;
      const int km = (k2 <= 512) ? k2 : (1024 - k2);
      const float2 Zk = Bb[km];
      const float2 Zn = Bb[(1024 - km) & 1023];
      const float xwr = 0.5f * (Zk.x + Zn.x);
      const float xwi = 0.5f * (Zk.y - Zn.y);
      const float xfr = 0.5f * (Zk.y + Zn.y);
      const float xfi = -0.5f * (Zk.x - Zn.x);
      const float pw = xwr * xwr + xwi * xwi;
      const float pf = xfr * xfr + xfi * xfi;
      A[k2] = make_float2(pw * 1024.0f, pf);
    }
    __syncthreads();   // all Bb reads done; A ready for fft2

    fft1024p(A, Bb, tw, tid);  // Bb[n].x = 2^20*ac_w[n], Bb[n].y = 1024*ac_f[n]

    // ---- fused partials: pitch + centroid + acds share ONE barrier ----
    float pv = -3.0e38f;
    int   pl = 1 << 30;
    for (int l = 44 + tid; l <= 441; l += 256) {
      const float v = Bb[l].y;
      if (v > pv) { pv = v; pl = l; }
    }
    #pragma unroll
    for (int m = 1; m < 64; m <<= 1) {
      const float ov = __shfl_xor(pv, m, 64);
      const int   ol = __shfl_xor(pl, m, 64);
      if (ov > pv || (ov == pv && ol < pl)) { pv = ov; pl = ol; }
    }
    cs0 = waveReduceSum(cs0);
    cs1 = waveReduceSum(cs1);
    if (lane == 0) { sred[w] = pv; sredi[w] = pl; sred[4 + w] = cs0; sred[8 + w] = cs1; }
    const float pwW = myPw * wgt462;
    #pragma unroll
    for (int l = 0; l < 11; ++l) {
      const float t = waveReduceSum(pwW * ctab[l]);
      if (lane == 0) aprt[w][l] = t;
    }
    __syncthreads();

    // finalizers (no barrier after; next phase's pre-fft1 barrier orders reuse)
    if (tid == 0) {
      float bv = sred[0]; int bl = sredi[0];
      #pragma unroll
      for (int q = 1; q < 4; ++q)
        if (sred[q] > bv || (sred[q] == bv && sredi[q] < bl)) { bv = sred[q]; bl = sredi[q]; }
      const float ac0  = Bb[0].y * (1.0f / 1024.0f);
      const float peak = bv * (1.0f / 1024.0f);
      const float nccf = peak / (ac0 + 1e-9f);
      out[PITCH_OFF + fg] = logf(22050.0f / (float)bl);
      out[VOI_OFF + fg]   = (nccf > 0.3f) ? 1.0f : 0.0f;
      out[nccf_off + fg]  = nccf;
      out[EN_OFF + fg]    = 10.0f * log10f(ac0 + 1e-10f);    // Parseval
      const float c0 = sred[4] + sred[5] + sred[6] + sred[7];
      const float c1 = sred[8] + sred[9] + sred[10] + sred[11];
      out[CEN_OFF + fg]   = c1 / (c0 + 1e-10f);
      const float a0 = aprt[0][0] + aprt[1][0] + aprt[2][0] + aprt[3][0];
      const float a1 = aprt[0][1] + aprt[1][1] + aprt[2][1] + aprt[3][1];
      out[TILT_OFF + fg]  = a1 / (a0 + 1e-10f);
    }
    if (tid < 11)
      stash[p][31 + tid] = aprt[0][tid] + aprt[1][tid] + aprt[2][tid] + aprt[3][tid];
    if (tid < 31) stash[p][tid] = Bb[tid].x * (1.0f / 1048576.0f);  // normalized r30
  }
  __syncthreads();   // stash visible to wave 0 for the tails

  // ---- deferred tails: up to SIX frames packed into wave 0 (6 x 10-lane groups);
  //      waves 1-3 exit. Per-group math identical to round-11 (proven).
  if (w == 0) {
    const int g     = lane / 10;            // 0..6 (g=6: lanes 60-63, inactive)
    const int ri    = lane - g * 10;        // 0..9
    const int gbase = g * 10;
    const int gg    = (g < FPB) ? g : (FPB - 1);   // clamp for safe LDS reads
    const bool act  = (g < np);
    const int fg    = fbase + gg;

    levinson_f30(&stash[gg][0],
                 (ri == 0 && act) ? (out + RC_OFF + (size_t)fg * 30) : (float*)nullptr);

    double rds[11], a10[11];
    #pragma unroll
    for (int l = 0; l < 11; ++l) rds[l] = (double)stash[gg][31 + l];
    levinson_d<10>(rds, a10);

    // Durand-Kerner in f64: group lane ri owns root ri; Jacobi via shfl in-group
    double zr = 0.4, zi = 0.9;
    for (int q = 0; q < ri; ++q) {
      const double nr = zr * 0.4 - zi * 0.9;
      zi = zr * 0.9 + zi * 0.4;
      zr = nr;
    }
    for (int it = 0; it < 60; ++it) {
      double pr = 1.0, pi = 0.0;            // Horner, c[0]=1
      #pragma unroll
      for (int q = 1; q <= 10; ++q) {
        const double nr = pr * zr - pi * zi + a10[q];
        pi = pr * zi + pi * zr;
        pr = nr;
      }
      double dr = 1.0, di = 0.0;
      #pragma unroll
      for (int j = 0; j < 10; ++j) {
        const double ozr = __shfl(zr, gbase + j, 64);
        const double ozi = __shfl(zi, gbase + j, 64);
        const double er = (j == ri) ? 1.0 : (zr - ozr);
        const double ei = (j == ri) ? 0.0 : (zi - ozi);
        const double nr = dr * er - di * ei;
        di = dr * ei + di * er;
        dr = nr;
      }
      dr += 1e-12;
      const double inv = 1.0 / (dr * dr + di * di);   // one divide, two mults
      const double qr = (pr * dr + pi * di) * inv;
      const double qi = (pi * dr - pr * di) * inv;
      zr -= qr;
      zi -= qi;
    }
    const double ang = atan2(zi, zr);
    double freq = (ang > 0.0001) ? (ang / 6.283185307179586476925287 * 10000.0) : 5000.0;
    if (ri >= 10) freq = 1.0e300;

    // gather all 10 freqs of the group, then stable 4-min select (lowest j on ties)
    double f[10];
    #pragma unroll
    for (int j = 0; j < 10; ++j) f[j] = __shfl(freq, gbase + j, 64);
    bool used[10];
    #pragma unroll
    for (int j = 0; j < 10; ++j) used[j] = false;
    float o4[4];
    #pragma unroll
    for (int p2 = 0; p2 < 4; ++p2) {
      double mn = 1.0e300;
      int mj = -1;
      #pragma unroll
      for (int j = 0; j < 10; ++j)
        if (!used[j] && f[j] < mn) { mn = f[j]; mj = j; }
      if (mj >= 0) used[mj] = true;
      o4[p2] = (float)mn;
    }
    if (ri == 0 && act) {
      out[(size_t)fg * 4 + 0] = o4[0];
      out[(size_t)fg * 4 + 1] = o4[1];
      out[(size_t)fg * 4 + 2] = o4[2];
      out[(size_t)fg * 4 + 3] = o4[3];
    }
  }
}

extern "C" void kernel_launch(void* const* d_in, const int* in_sizes, int n_in,
                              void* d_out, int out_size, void* d_ws, size_t ws_size,
                              hipStream_t stream) {
  (void)in_sizes; (void)n_in; (void)d_ws; (void)ws_size;
  const float* x = (const float*)d_in[0];
  float* out = (float*)d_out;
  int xds_pf = 232;
  if (out_size >= XDS_OFF + NFTOT * 464 + NFTOT) xds_pf = 464;
  const int nccf_off = XDS_OFF + NFTOT * xds_pf;
  feat_mono6<<<dim3(NBLK), dim3(256), 0, stream>>>(x, out, xds_pf, nccf_off);
}